// Round 2
// baseline (332.912 us; speedup 1.0000x reference)
//
#include <hip/hip_runtime.h>

// CorrelationPyramid on MI355X — round 6: LDS-free direct-gather projection.
//
// Pipeline (7 dispatches):
//   0) prep_weights: one-shot fp32 -> f16 conversion of the 64x128 projection
//                    matrix (A-fragments then load as single 16B L2-hot reads).
//   1) proj_mfma   : 1x1 conv C=128 -> 64 via mfma_f32_16x16x32_f16.
//                    NO LDS, NO barrier: each lane gathers its B-fragment
//                    channels directly from global NCHW (same 64 strided
//                    loads/thread the LDS path needed, each element read
//                    exactly once per block). Round-5 lesson: the compiler
//                    re-sinks register-array prefetches (VGPR stayed 68), so
//                    latency must be hidden by OCCUPANCY, not per-thread
//                    batching: 0 B LDS + launch_bounds(256,4) -> ~16 waves/CU
//                    (2x round-5) and no barrier-lockstep between gather and
//                    MFMA phases. Fused level-0 L2-normalize + f16 epilogue.
//   2) pool_all    : fused 4x4 pool chain + per-level normalize -> f16 for
//                    levels 1-3 (one dispatch, no fp32 intermediates).
//   3) corr_mfma<R> x4: one WAVE per (bn, h, w-tile), no LDS, no barriers;
//                    bn = blockIdx%8 pins each value image to one XCD's L2.

typedef _Float16 f16;
typedef _Float16 f16x4 __attribute__((ext_vector_type(4)));
typedef _Float16 f16x8 __attribute__((ext_vector_type(8)));
typedef float f32x4 __attribute__((ext_vector_type(4)));

#define EPSN 1e-12f

// ---------------- one-shot weight fp32 -> f16 ----------------
__global__ __launch_bounds__(256) void prep_weights(
    const float* __restrict__ wt, f16* __restrict__ wh) {
  int gid = blockIdx.x * 256 + threadIdx.x;   // 2048 threads x 4 elems = 8192
  float4 w = *(const float4*)(wt + gid * 4);
  f16x4 h;
  h[0] = (f16)w.x; h[1] = (f16)w.y; h[2] = (f16)w.z; h[3] = (f16)w.w;
  *(f16x4*)(wh + gid * 4) = h;
}

// ---------------- projection via MFMA, fused level-0 normalize ----------------
// Block = 256 threads = 4 waves; block covers 128 consecutive pixels.
// Wave wv covers pixels (2wv..2wv+2)*16; lane (cl,quad) gathers channels
// kc*32+quad*8..+8 of pixels w0+cl and w0+16+cl. No LDS, no __syncthreads.
__global__ __launch_bounds__(256, 4) void proj_mfma(
    const float* __restrict__ xq, const float* __restrict__ xv,
    const f16* __restrict__ wh, const float* __restrict__ bias,
    float* __restrict__ outf, f16* __restrict__ outh, int P) {
  int bid = blockIdx.x;
  int img = bid / 200;           // 10 images: 0,1 = query; 2..9 = values
  int p0 = (bid - img * 200) * 128;
  const float* xsrc = (img < 2) ? (xq + (size_t)img * 128 * P)
                                : (xv + (size_t)(img - 2) * 128 * P);

  int tid = threadIdx.x;
  int lane = tid & 63;
  int wv = tid >> 6;
  int cl = lane & 15;
  int quad = lane >> 4;

  // this lane's gather base: channel quad*8, pixel p0 + 2wv*16 + cl
  const float* xp = xsrc + (size_t)(quad * 8) * P + p0 + (2 * wv) * 16 + cl;

  f32x4 acc[2][4];
#pragma unroll
  for (int a = 0; a < 2; ++a)
#pragma unroll
    for (int m = 0; m < 4; ++m) acc[a][m] = (f32x4)0.f;

#pragma unroll
  for (int kc = 0; kc < 4; ++kc) {
    // 16 independent strided global loads (two pixel tiles x 8 channels)
    float v0[8], v1[8];
#pragma unroll
    for (int k = 0; k < 8; ++k) {
      const float* c = xp + (size_t)(kc * 32 + k) * P;
      v0[k] = c[0];
      v1[k] = c[16];
    }
    f16x8 b0, b1;
#pragma unroll
    for (int k = 0; k < 8; ++k) { b0[k] = (f16)v0[k]; b1[k] = (f16)v1[k]; }
    f16x8 afr[4];
#pragma unroll
    for (int mt = 0; mt < 4; ++mt)
      afr[mt] = *(const f16x8*)(wh + (mt * 16 + cl) * 128 + kc * 32 + quad * 8);
#pragma unroll
    for (int mt = 0; mt < 4; ++mt) {
      acc[0][mt] = __builtin_amdgcn_mfma_f32_16x16x32_f16(afr[mt], b0, acc[0][mt], 0, 0, 0);
      acc[1][mt] = __builtin_amdgcn_mfma_f32_16x16x32_f16(afr[mt], b1, acc[1][mt], 0, 0, 0);
    }
  }

  float4 bi[4];
#pragma unroll
  for (int mt = 0; mt < 4; ++mt) bi[mt] = *(const float4*)(bias + mt * 16 + quad * 4);

#pragma unroll
  for (int pt = 0; pt < 2; ++pt) {
    int px = p0 + (2 * wv + pt) * 16 + cl;
    float ss = 0.f;
#pragma unroll
    for (int mt = 0; mt < 4; ++mt) {
      acc[pt][mt][0] += bi[mt].x;
      acc[pt][mt][1] += bi[mt].y;
      acc[pt][mt][2] += bi[mt].z;
      acc[pt][mt][3] += bi[mt].w;
#pragma unroll
      for (int r = 0; r < 4; ++r) ss = fmaf(acc[pt][mt][r], acc[pt][mt][r], ss);
    }
    ss += __shfl_xor(ss, 16, 64);
    ss += __shfl_xor(ss, 32, 64);
    float s = 1.0f / fmaxf(sqrtf(ss), EPSN);
    size_t base = ((size_t)img * P + px) * 64;
#pragma unroll
    for (int mt = 0; mt < 4; ++mt) {
      *(float4*)(outf + base + mt * 16 + quad * 4) =
          make_float4(acc[pt][mt][0], acc[pt][mt][1], acc[pt][mt][2], acc[pt][mt][3]);
      f16x4 hn;
      hn[0] = (f16)(acc[pt][mt][0] * s);
      hn[1] = (f16)(acc[pt][mt][1] * s);
      hn[2] = (f16)(acc[pt][mt][2] * s);
      hn[3] = (f16)(acc[pt][mt][3] * s);
      *(f16x4*)(outh + base + mt * 16 + quad * 4) = hn;
    }
  }
}

// ---------------- fused 4x4 pool + per-level L2-normalize -> f16 -------------
// One thread = 4 channels (c4) of one L2 (40x40) output pixel.
// 16-lane group (c4=0..15) = all 64 channels of that pixel.
// 4 groups of a wave (g = (tid>>4)&3) = a 2x2 block of L2 pixels -> one L3
// pixel via shfl_xor(16/32).
// Emits: qh1 (80x80 f16 norm), qh2 (40x40), qh3 (20x20). No fp32 intermediates.
__global__ __launch_bounds__(256) void pool_all(
    const float* __restrict__ q0, f16* __restrict__ qh1,
    f16* __restrict__ qh2, f16* __restrict__ qh3) {
  int gid = blockIdx.x * 256 + threadIdx.x;   // total = 10*20*20*64 = 256000
  int c4 = gid & 15;
  int g = (gid >> 4) & 3;
  int idx = gid >> 6;            // [0, 4000)
  int w3 = idx % 20;
  int t = idx / 20;
  int h3 = t % 20;
  int img = t / 20;
  int h2 = 2 * h3 + (g >> 1);
  int w2 = 2 * w3 + (g & 1);

  const float4* in4 = (const float4*)q0;
  size_t base = ((size_t)(img * 160 + 4 * h2) * 160 + 4 * w2) * 16 + c4;
  float4 a[16];
#pragma unroll
  for (int i = 0; i < 4; ++i)
#pragma unroll
    for (int j = 0; j < 4; ++j)
      a[i * 4 + j] = in4[base + (size_t)i * 160 * 16 + j * 16];

  // level-1 pixels (2x2 of them) + level-2 pixel
  float4 v1[4];
  float4 q2v = make_float4(0.f, 0.f, 0.f, 0.f);
#pragma unroll
  for (int i1 = 0; i1 < 2; ++i1)
#pragma unroll
    for (int j1 = 0; j1 < 2; ++j1) {
      float4 s00 = a[(2 * i1) * 4 + 2 * j1];
      float4 s01 = a[(2 * i1) * 4 + 2 * j1 + 1];
      float4 s10 = a[(2 * i1 + 1) * 4 + 2 * j1];
      float4 s11 = a[(2 * i1 + 1) * 4 + 2 * j1 + 1];
      float4 r;
      r.x = 0.25f * (s00.x + s01.x + s10.x + s11.x);
      r.y = 0.25f * (s00.y + s01.y + s10.y + s11.y);
      r.z = 0.25f * (s00.z + s01.z + s10.z + s11.z);
      r.w = 0.25f * (s00.w + s01.w + s10.w + s11.w);
      v1[i1 * 2 + j1] = r;
      q2v.x += r.x; q2v.y += r.y; q2v.z += r.z; q2v.w += r.w;
    }
  q2v.x *= 0.25f; q2v.y *= 0.25f; q2v.z *= 0.25f; q2v.w *= 0.25f;

  // level-1: normalize + write f16
#pragma unroll
  for (int i1 = 0; i1 < 2; ++i1)
#pragma unroll
    for (int j1 = 0; j1 < 2; ++j1) {
      float4 r = v1[i1 * 2 + j1];
      float ss = fmaf(r.x, r.x, fmaf(r.y, r.y, fmaf(r.z, r.z, r.w * r.w)));
      ss += __shfl_xor(ss, 1, 64);
      ss += __shfl_xor(ss, 2, 64);
      ss += __shfl_xor(ss, 4, 64);
      ss += __shfl_xor(ss, 8, 64);
      float s = 1.0f / fmaxf(sqrtf(ss), EPSN);
      int y1 = 2 * h2 + i1, x1 = 2 * w2 + j1;
      f16x4 h;
      h[0] = (f16)(r.x * s); h[1] = (f16)(r.y * s);
      h[2] = (f16)(r.z * s); h[3] = (f16)(r.w * s);
      *(f16x4*)(qh1 + ((size_t)(img * 80 + y1) * 80 + x1) * 64 + c4 * 4) = h;
    }

  // level-2: normalize + write f16
  {
    float ss = fmaf(q2v.x, q2v.x, fmaf(q2v.y, q2v.y, fmaf(q2v.z, q2v.z, q2v.w * q2v.w)));
    ss += __shfl_xor(ss, 1, 64);
    ss += __shfl_xor(ss, 2, 64);
    ss += __shfl_xor(ss, 4, 64);
    ss += __shfl_xor(ss, 8, 64);
    float s = 1.0f / fmaxf(sqrtf(ss), EPSN);
    f16x4 h;
    h[0] = (f16)(q2v.x * s); h[1] = (f16)(q2v.y * s);
    h[2] = (f16)(q2v.z * s); h[3] = (f16)(q2v.w * s);
    *(f16x4*)(qh2 + ((size_t)(img * 40 + h2) * 40 + w2) * 64 + c4 * 4) = h;
  }

  // level-3: cross-group (2x2 L2 pixels) average, normalize, write from g==0
  {
    float4 q3v;
    q3v.x = q2v.x + __shfl_xor(q2v.x, 16, 64);
    q3v.y = q2v.y + __shfl_xor(q2v.y, 16, 64);
    q3v.z = q2v.z + __shfl_xor(q2v.z, 16, 64);
    q3v.w = q2v.w + __shfl_xor(q2v.w, 16, 64);
    q3v.x += __shfl_xor(q3v.x, 32, 64);
    q3v.y += __shfl_xor(q3v.y, 32, 64);
    q3v.z += __shfl_xor(q3v.z, 32, 64);
    q3v.w += __shfl_xor(q3v.w, 32, 64);
    q3v.x *= 0.25f; q3v.y *= 0.25f; q3v.z *= 0.25f; q3v.w *= 0.25f;
    float ss = fmaf(q3v.x, q3v.x, fmaf(q3v.y, q3v.y, fmaf(q3v.z, q3v.z, q3v.w * q3v.w)));
    ss += __shfl_xor(ss, 1, 64);
    ss += __shfl_xor(ss, 2, 64);
    ss += __shfl_xor(ss, 4, 64);
    ss += __shfl_xor(ss, 8, 64);
    float s = 1.0f / fmaxf(sqrtf(ss), EPSN);
    if (g == 0) {
      f16x4 h;
      h[0] = (f16)(q3v.x * s); h[1] = (f16)(q3v.y * s);
      h[2] = (f16)(q3v.z * s); h[3] = (f16)(q3v.w * s);
      *(f16x4*)(qh3 + ((size_t)(img * 20 + h3) * 20 + w3) * 64 + c4 * 4) = h;
    }
  }
}

// ---------------- correlation: one wave per (bn, h, w-tile) ----------------
// No LDS, no barriers. Band tiles: T0 cols (w0-R+cl) mod W -> D rows 0-7
// (quads 0,1), dxi = r - cl + 2R;  T1 cols (w0+R+cl) mod W -> rows 8-15
// (quads 2,3), dxi = r - cl.  Exact partition for R <= 4. Each (w,dy,dx)
// written exactly once; partial w-tiles (W%16) masked on store.
// C/D layout: col = lane&15, row = (lane>>4)*4 + reg.
template <int R>
__global__ __launch_bounds__(256, 8) void corr_mfma(
    const f16* __restrict__ qh, const f16* __restrict__ vh,
    float* __restrict__ out, int H, int W, int T) {
  constexpr int D = 2 * R + 1, DD = D * D;
  int bn = blockIdx.x & 7;               // 8 bn values -> 8 XCDs (heuristic)
  int wv = threadIdx.x >> 6;
  int widx = (blockIdx.x >> 3) * 4 + wv; // [0, H*T)
  int h = widx / T;
  int wt = widx - h * T;
  int lane = threadIdx.x & 63;
  int cl = lane & 15, quad = lane >> 4;
  int b = bn >> 2;
  int w0 = wt * 16;

  // A fragments (q row), loaded once
  int ap = w0 + cl; if (ap >= W) ap = W - 1;   // clamp partial tile
  const f16* qp = qh + ((size_t)(b * H + h) * W + ap) * 64 + quad * 8;
  f16x8 a0 = *(const f16x8*)qp;
  f16x8 a1 = *(const f16x8*)(qp + 32);

  // B pixel offsets (roll wraparound), fixed across dy
  int c0 = w0 - R + cl; if (c0 < 0) c0 += W; if (c0 >= W) c0 -= W;
  int c1 = w0 + R + cl; if (c1 >= W) c1 -= W;
  int b0off = c0 * 64 + quad * 8;
  int b1off = c1 * 64 + quad * 8;

  // store offsets: out[pix*DD + dyi*D + dxi], pix = (bn*H+h)*W + w
  int rbase = quad * 4;
  int base_dxi = rbase - cl + ((quad < 2) ? 2 * R : 0);
  int wr0 = w0 + rbase;
  int off0 = ((bn * H + h) * W + wr0) * DD + base_dxi;

  for (int dyi = 0; dyi < D; ++dyi) {
    int h2 = h - dyi + R; if (h2 < 0) h2 += H; else if (h2 >= H) h2 -= H;
    const f16* vrow = vh + ((size_t)(bn * H + h2) * W) * 64;
    f16x8 b0a = *(const f16x8*)(vrow + b0off);
    f16x8 b0b = *(const f16x8*)(vrow + b0off + 32);
    f16x8 b1a = *(const f16x8*)(vrow + b1off);
    f16x8 b1b = *(const f16x8*)(vrow + b1off + 32);
    f32x4 A0 = __builtin_amdgcn_mfma_f32_16x16x32_f16(a0, b0a, (f32x4)0.f, 0, 0, 0);
    A0 = __builtin_amdgcn_mfma_f32_16x16x32_f16(a1, b0b, A0, 0, 0, 0);
    f32x4 A1 = __builtin_amdgcn_mfma_f32_16x16x32_f16(a0, b1a, (f32x4)0.f, 0, 0, 0);
    A1 = __builtin_amdgcn_mfma_f32_16x16x32_f16(a1, b1b, A1, 0, 0, 0);
#pragma unroll
    for (int rr = 0; rr < 4; ++rr) {
      int dxi = base_dxi + rr;
      float val = (quad < 2) ? A0[rr] : A1[rr];
      if ((unsigned)dxi <= (unsigned)(2 * R) && (wr0 + rr) < W)
        out[off0 + dyi * D + rr * (DD + 1)] = val;
    }
  }
}

extern "C" void kernel_launch(void* const* d_in, const int* in_sizes, int n_in,
                              void* d_out, int out_size, void* d_ws, size_t ws_size,
                              hipStream_t stream) {
  const float* query  = (const float*)d_in[0];   // [2,128,160,160]
  const float* values = (const float*)d_in[1];   // [2,4,128,160,160]
  const float* pw     = (const float*)d_in[2];   // [64,128]
  const float* pb     = (const float*)d_in[3];   // [64]
  float* out = (float*)d_out;
  float* ws  = (float*)d_ws;

  const int B = 2, N = 4;
  const int P0 = 160 * 160;

  // Workspace layout (floats):
  //   [0, 10*P0*64)            q0+v0 un-normalized fp32 NHWC (proj out, pool in)
  //   then level-0 f16 (10 images), levels 1-3 f16 (10 images each), wh.
  float* q0 = ws;
  f16* q0h = (f16*)(ws + (size_t)10 * P0 * 64);
  f16* v0h = q0h + (size_t)2 * P0 * 64;
  f16* qh1 = q0h + (size_t)10 * P0 * 64;
  f16* vh1 = qh1 + (size_t)2 * (P0 / 4) * 64;
  f16* qh2 = vh1 + (size_t)8 * (P0 / 4) * 64;
  f16* vh2 = qh2 + (size_t)2 * (P0 / 16) * 64;
  f16* qh3 = vh2 + (size_t)8 * (P0 / 16) * 64;
  f16* vh3 = qh3 + (size_t)2 * (P0 / 64) * 64;
  f16* wh  = vh3 + (size_t)8 * (P0 / 64) * 64;   // 8192 f16

  // 0) one-shot weight conversion
  prep_weights<<<8, 256, 0, stream>>>(pw, wh);

  // 1) projection via MFMA, fused level-0 norm+f16
  proj_mfma<<<2000, 256, 0, stream>>>(query, values, wh, pb, q0, q0h, P0);

  // 2) fused pool+norm chain: one dispatch produces levels 1-3 f16
  pool_all<<<1000, 256, 0, stream>>>(q0, qh1, qh2, qh3);

  // 3) correlation (output tuple concatenated flat)
  float* out0 = out;
  float* out1 = out0 + (size_t)B * N * P0 * 81;
  float* out2 = out1 + (size_t)B * N * (P0 / 4) * 25;
  float* out3 = out2 + (size_t)B * N * (P0 / 16) * 9;
  // waves = 8*H*T; blocks = waves/4 (all divisible by 8)
  corr_mfma<4><<<8 * 160 * 10 / 4, 256, 0, stream>>>(q0h, v0h, out0, 160, 160, 10);
  corr_mfma<2><<<8 * 80 * 5 / 4, 256, 0, stream>>>(qh1, vh1, out1, 80, 80, 5);
  corr_mfma<1><<<8 * 40 * 3 / 4, 256, 0, stream>>>(qh2, vh2, out2, 40, 40, 3);
  corr_mfma<1><<<8 * 20 * 2 / 4, 256, 0, stream>>>(qh3, vh3, out3, 20, 20, 2);
}

// Round 3
// 321.891 us; speedup vs baseline: 1.0342x; 1.0342x over previous
//
#include <hip/hip_runtime.h>

// CorrelationPyramid on MI355X — round 7: coalesced-staged MFMA projection.
//
// Round-5/6 lesson: per-thread scalar gathers (4 B/lane, 256 B/wave-instr)
// can never cover the latency-BW product (~36 wave-instrs in flight needed;
// the compiler pipelines ~4 deep regardless of source structure). Fat float4
// loads need only ~9 in flight -> stage COALESCED along pixels into LDS and
// do the channel->lane transpose on the LDS-read side instead.
//
// Pipeline (7 dispatches):
//   0) prep_weights: one-shot fp32 -> f16 of the 64x128 projection matrix.
//   1) proj_mfma   : block = 64 px x 128 ch. Stage: 8x float4/thread,
//                    ds_write_b128 into fp32 LDS [c][68] with rotation
//                    swizzle x=(px+8*((c>>3)&3))&63 (write & read agree).
//                    Frag reads: 8x ds_read_b32, banks cl+8*quad -> 2-way
//                    (free). One barrier. MFMA + fused L0 normalize + f16
//                    epilogue identical to round 6 (same numerics).
//   2) pool_all    : fused 4x4 pool chain + per-level normalize -> f16.
//   3) corr_mfma<R> x4: one WAVE per (bn, h, w-tile), no LDS, no barriers;
//                    bn = blockIdx%8 pins each value image to one XCD's L2.

typedef _Float16 f16;
typedef _Float16 f16x4 __attribute__((ext_vector_type(4)));
typedef _Float16 f16x8 __attribute__((ext_vector_type(8)));
typedef float f32x4 __attribute__((ext_vector_type(4)));

#define EPSN 1e-12f

// ---------------- one-shot weight fp32 -> f16 ----------------
__global__ __launch_bounds__(256) void prep_weights(
    const float* __restrict__ wt, f16* __restrict__ wh) {
  int gid = blockIdx.x * 256 + threadIdx.x;   // 2048 threads x 4 elems = 8192
  float4 w = *(const float4*)(wt + gid * 4);
  f16x4 h;
  h[0] = (f16)w.x; h[1] = (f16)w.y; h[2] = (f16)w.z; h[3] = (f16)w.w;
  *(f16x4*)(wh + gid * 4) = h;
}

// ---------------- projection via MFMA, fused level-0 normalize ----------------
// Block = 256 threads = 4 waves, covers 64 consecutive pixels x 128 channels.
// LDS: fp32 [128][68], value at [c][(px + 8*((c>>3)&3)) & 63].
#define LROW 68

__global__ __launch_bounds__(256, 4) void proj_mfma(
    const float* __restrict__ xq, const float* __restrict__ xv,
    const f16* __restrict__ wh, const float* __restrict__ bias,
    float* __restrict__ outf, f16* __restrict__ outh, int P) {
  __shared__ float xs[128 * LROW];   // 34,816 B

  int bid = blockIdx.x;
  int img = bid / 400;           // 10 images: 0,1 = query; 2..9 = values
  int p0 = (bid - img * 400) * 64;
  const float* xsrc = (img < 2) ? (xq + (size_t)img * 128 * P)
                                : (xv + (size_t)(img - 2) * 128 * P);

  int tid = threadIdx.x;
  int lane = tid & 63;
  int wv = tid >> 6;
  int cl = lane & 15;
  int quad = lane >> 4;

  // ---- stage: coalesced float4 loads, swizzled b128 LDS writes ----
  {
    int cb = tid >> 4;            // 0..15
    int pxg = (tid & 15) * 4;     // 0..60
#pragma unroll
    for (int i = 0; i < 8; ++i) {
      int c = cb + 16 * i;
      float4 v = *(const float4*)(xsrc + (size_t)c * P + p0 + pxg);
      int x = (pxg + 8 * ((c >> 3) & 3)) & 63;
      *(float4*)(xs + c * LROW + x) = v;
    }
  }
  __syncthreads();

  // ---- MFMA: wave wv owns pixel tile [wv*16, wv*16+16) ----
  f32x4 acc[4];
#pragma unroll
  for (int m = 0; m < 4; ++m) acc[m] = (f32x4)0.f;

  int pxl = wv * 16 + cl;                       // local pixel this lane owns
  int xr = (pxl + 8 * quad) & 63;               // rot(c) == 8*quad for frags

#pragma unroll
  for (int kc = 0; kc < 4; ++kc) {
    f16x8 bfr;
#pragma unroll
    for (int k = 0; k < 8; ++k) {
      int c = kc * 32 + quad * 8 + k;
      bfr[k] = (f16)xs[c * LROW + xr];
    }
    f16x8 afr[4];
#pragma unroll
    for (int mt = 0; mt < 4; ++mt)
      afr[mt] = *(const f16x8*)(wh + (mt * 16 + cl) * 128 + kc * 32 + quad * 8);
#pragma unroll
    for (int mt = 0; mt < 4; ++mt)
      acc[mt] = __builtin_amdgcn_mfma_f32_16x16x32_f16(afr[mt], bfr, acc[mt], 0, 0, 0);
  }

  float4 bi[4];
#pragma unroll
  for (int mt = 0; mt < 4; ++mt) bi[mt] = *(const float4*)(bias + mt * 16 + quad * 4);

  int px = p0 + pxl;
  float ss = 0.f;
#pragma unroll
  for (int mt = 0; mt < 4; ++mt) {
    acc[mt][0] += bi[mt].x;
    acc[mt][1] += bi[mt].y;
    acc[mt][2] += bi[mt].z;
    acc[mt][3] += bi[mt].w;
#pragma unroll
    for (int r = 0; r < 4; ++r) ss = fmaf(acc[mt][r], acc[mt][r], ss);
  }
  ss += __shfl_xor(ss, 16, 64);
  ss += __shfl_xor(ss, 32, 64);
  float s = 1.0f / fmaxf(sqrtf(ss), EPSN);
  size_t base = ((size_t)img * P + px) * 64;
#pragma unroll
  for (int mt = 0; mt < 4; ++mt) {
    *(float4*)(outf + base + mt * 16 + quad * 4) =
        make_float4(acc[mt][0], acc[mt][1], acc[mt][2], acc[mt][3]);
    f16x4 hn;
    hn[0] = (f16)(acc[mt][0] * s);
    hn[1] = (f16)(acc[mt][1] * s);
    hn[2] = (f16)(acc[mt][2] * s);
    hn[3] = (f16)(acc[mt][3] * s);
    *(f16x4*)(outh + base + mt * 16 + quad * 4) = hn;
  }
}

// ---------------- fused 4x4 pool + per-level L2-normalize -> f16 -------------
// One thread = 4 channels (c4) of one L2 (40x40) output pixel.
// 16-lane group (c4=0..15) = all 64 channels of that pixel.
// 4 groups of a wave (g = (tid>>4)&3) = a 2x2 block of L2 pixels -> one L3
// pixel via shfl_xor(16/32).
// Emits: qh1 (80x80 f16 norm), qh2 (40x40), qh3 (20x20). No fp32 intermediates.
__global__ __launch_bounds__(256) void pool_all(
    const float* __restrict__ q0, f16* __restrict__ qh1,
    f16* __restrict__ qh2, f16* __restrict__ qh3) {
  int gid = blockIdx.x * 256 + threadIdx.x;   // total = 10*20*20*64 = 256000
  int c4 = gid & 15;
  int g = (gid >> 4) & 3;
  int idx = gid >> 6;            // [0, 4000)
  int w3 = idx % 20;
  int t = idx / 20;
  int h3 = t % 20;
  int img = t / 20;
  int h2 = 2 * h3 + (g >> 1);
  int w2 = 2 * w3 + (g & 1);

  const float4* in4 = (const float4*)q0;
  size_t base = ((size_t)(img * 160 + 4 * h2) * 160 + 4 * w2) * 16 + c4;
  float4 a[16];
#pragma unroll
  for (int i = 0; i < 4; ++i)
#pragma unroll
    for (int j = 0; j < 4; ++j)
      a[i * 4 + j] = in4[base + (size_t)i * 160 * 16 + j * 16];

  // level-1 pixels (2x2 of them) + level-2 pixel
  float4 v1[4];
  float4 q2v = make_float4(0.f, 0.f, 0.f, 0.f);
#pragma unroll
  for (int i1 = 0; i1 < 2; ++i1)
#pragma unroll
    for (int j1 = 0; j1 < 2; ++j1) {
      float4 s00 = a[(2 * i1) * 4 + 2 * j1];
      float4 s01 = a[(2 * i1) * 4 + 2 * j1 + 1];
      float4 s10 = a[(2 * i1 + 1) * 4 + 2 * j1];
      float4 s11 = a[(2 * i1 + 1) * 4 + 2 * j1 + 1];
      float4 r;
      r.x = 0.25f * (s00.x + s01.x + s10.x + s11.x);
      r.y = 0.25f * (s00.y + s01.y + s10.y + s11.y);
      r.z = 0.25f * (s00.z + s01.z + s10.z + s11.z);
      r.w = 0.25f * (s00.w + s01.w + s10.w + s11.w);
      v1[i1 * 2 + j1] = r;
      q2v.x += r.x; q2v.y += r.y; q2v.z += r.z; q2v.w += r.w;
    }
  q2v.x *= 0.25f; q2v.y *= 0.25f; q2v.z *= 0.25f; q2v.w *= 0.25f;

  // level-1: normalize + write f16
#pragma unroll
  for (int i1 = 0; i1 < 2; ++i1)
#pragma unroll
    for (int j1 = 0; j1 < 2; ++j1) {
      float4 r = v1[i1 * 2 + j1];
      float ss = fmaf(r.x, r.x, fmaf(r.y, r.y, fmaf(r.z, r.z, r.w * r.w)));
      ss += __shfl_xor(ss, 1, 64);
      ss += __shfl_xor(ss, 2, 64);
      ss += __shfl_xor(ss, 4, 64);
      ss += __shfl_xor(ss, 8, 64);
      float s = 1.0f / fmaxf(sqrtf(ss), EPSN);
      int y1 = 2 * h2 + i1, x1 = 2 * w2 + j1;
      f16x4 h;
      h[0] = (f16)(r.x * s); h[1] = (f16)(r.y * s);
      h[2] = (f16)(r.z * s); h[3] = (f16)(r.w * s);
      *(f16x4*)(qh1 + ((size_t)(img * 80 + y1) * 80 + x1) * 64 + c4 * 4) = h;
    }

  // level-2: normalize + write f16
  {
    float ss = fmaf(q2v.x, q2v.x, fmaf(q2v.y, q2v.y, fmaf(q2v.z, q2v.z, q2v.w * q2v.w)));
    ss += __shfl_xor(ss, 1, 64);
    ss += __shfl_xor(ss, 2, 64);
    ss += __shfl_xor(ss, 4, 64);
    ss += __shfl_xor(ss, 8, 64);
    float s = 1.0f / fmaxf(sqrtf(ss), EPSN);
    f16x4 h;
    h[0] = (f16)(q2v.x * s); h[1] = (f16)(q2v.y * s);
    h[2] = (f16)(q2v.z * s); h[3] = (f16)(q2v.w * s);
    *(f16x4*)(qh2 + ((size_t)(img * 40 + h2) * 40 + w2) * 64 + c4 * 4) = h;
  }

  // level-3: cross-group (2x2 L2 pixels) average, normalize, write from g==0
  {
    float4 q3v;
    q3v.x = q2v.x + __shfl_xor(q2v.x, 16, 64);
    q3v.y = q2v.y + __shfl_xor(q2v.y, 16, 64);
    q3v.z = q2v.z + __shfl_xor(q2v.z, 16, 64);
    q3v.w = q2v.w + __shfl_xor(q2v.w, 16, 64);
    q3v.x += __shfl_xor(q3v.x, 32, 64);
    q3v.y += __shfl_xor(q3v.y, 32, 64);
    q3v.z += __shfl_xor(q3v.z, 32, 64);
    q3v.w += __shfl_xor(q3v.w, 32, 64);
    q3v.x *= 0.25f; q3v.y *= 0.25f; q3v.z *= 0.25f; q3v.w *= 0.25f;
    float ss = fmaf(q3v.x, q3v.x, fmaf(q3v.y, q3v.y, fmaf(q3v.z, q3v.z, q3v.w * q3v.w)));
    ss += __shfl_xor(ss, 1, 64);
    ss += __shfl_xor(ss, 2, 64);
    ss += __shfl_xor(ss, 4, 64);
    ss += __shfl_xor(ss, 8, 64);
    float s = 1.0f / fmaxf(sqrtf(ss), EPSN);
    if (g == 0) {
      f16x4 h;
      h[0] = (f16)(q3v.x * s); h[1] = (f16)(q3v.y * s);
      h[2] = (f16)(q3v.z * s); h[3] = (f16)(q3v.w * s);
      *(f16x4*)(qh3 + ((size_t)(img * 20 + h3) * 20 + w3) * 64 + c4 * 4) = h;
    }
  }
}

// ---------------- correlation: one wave per (bn, h, w-tile) ----------------
// No LDS, no barriers. Band tiles: T0 cols (w0-R+cl) mod W -> D rows 0-7
// (quads 0,1), dxi = r - cl + 2R;  T1 cols (w0+R+cl) mod W -> rows 8-15
// (quads 2,3), dxi = r - cl.  Exact partition for R <= 4. Each (w,dy,dx)
// written exactly once; partial w-tiles (W%16) masked on store.
// C/D layout: col = lane&15, row = (lane>>4)*4 + reg.
template <int R>
__global__ __launch_bounds__(256, 8) void corr_mfma(
    const f16* __restrict__ qh, const f16* __restrict__ vh,
    float* __restrict__ out, int H, int W, int T) {
  constexpr int D = 2 * R + 1, DD = D * D;
  int bn = blockIdx.x & 7;               // 8 bn values -> 8 XCDs (heuristic)
  int wv = threadIdx.x >> 6;
  int widx = (blockIdx.x >> 3) * 4 + wv; // [0, H*T)
  int h = widx / T;
  int wt = widx - h * T;
  int lane = threadIdx.x & 63;
  int cl = lane & 15, quad = lane >> 4;
  int b = bn >> 2;
  int w0 = wt * 16;

  // A fragments (q row), loaded once
  int ap = w0 + cl; if (ap >= W) ap = W - 1;   // clamp partial tile
  const f16* qp = qh + ((size_t)(b * H + h) * W + ap) * 64 + quad * 8;
  f16x8 a0 = *(const f16x8*)qp;
  f16x8 a1 = *(const f16x8*)(qp + 32);

  // B pixel offsets (roll wraparound), fixed across dy
  int c0 = w0 - R + cl; if (c0 < 0) c0 += W; if (c0 >= W) c0 -= W;
  int c1 = w0 + R + cl; if (c1 >= W) c1 -= W;
  int b0off = c0 * 64 + quad * 8;
  int b1off = c1 * 64 + quad * 8;

  // store offsets: out[pix*DD + dyi*D + dxi], pix = (bn*H+h)*W + w
  int rbase = quad * 4;
  int base_dxi = rbase - cl + ((quad < 2) ? 2 * R : 0);
  int wr0 = w0 + rbase;
  int off0 = ((bn * H + h) * W + wr0) * DD + base_dxi;

  for (int dyi = 0; dyi < D; ++dyi) {
    int h2 = h - dyi + R; if (h2 < 0) h2 += H; else if (h2 >= H) h2 -= H;
    const f16* vrow = vh + ((size_t)(bn * H + h2) * W) * 64;
    f16x8 b0a = *(const f16x8*)(vrow + b0off);
    f16x8 b0b = *(const f16x8*)(vrow + b0off + 32);
    f16x8 b1a = *(const f16x8*)(vrow + b1off);
    f16x8 b1b = *(const f16x8*)(vrow + b1off + 32);
    f32x4 A0 = __builtin_amdgcn_mfma_f32_16x16x32_f16(a0, b0a, (f32x4)0.f, 0, 0, 0);
    A0 = __builtin_amdgcn_mfma_f32_16x16x32_f16(a1, b0b, A0, 0, 0, 0);
    f32x4 A1 = __builtin_amdgcn_mfma_f32_16x16x32_f16(a0, b1a, (f32x4)0.f, 0, 0, 0);
    A1 = __builtin_amdgcn_mfma_f32_16x16x32_f16(a1, b1b, A1, 0, 0, 0);
#pragma unroll
    for (int rr = 0; rr < 4; ++rr) {
      int dxi = base_dxi + rr;
      float val = (quad < 2) ? A0[rr] : A1[rr];
      if ((unsigned)dxi <= (unsigned)(2 * R) && (wr0 + rr) < W)
        out[off0 + dyi * D + rr * (DD + 1)] = val;
    }
  }
}

extern "C" void kernel_launch(void* const* d_in, const int* in_sizes, int n_in,
                              void* d_out, int out_size, void* d_ws, size_t ws_size,
                              hipStream_t stream) {
  const float* query  = (const float*)d_in[0];   // [2,128,160,160]
  const float* values = (const float*)d_in[1];   // [2,4,128,160,160]
  const float* pw     = (const float*)d_in[2];   // [64,128]
  const float* pb     = (const float*)d_in[3];   // [64]
  float* out = (float*)d_out;
  float* ws  = (float*)d_ws;

  const int B = 2, N = 4;
  const int P0 = 160 * 160;

  // Workspace layout (floats):
  //   [0, 10*P0*64)            q0+v0 un-normalized fp32 NHWC (proj out, pool in)
  //   then level-0 f16 (10 images), levels 1-3 f16 (10 images each), wh.
  float* q0 = ws;
  f16* q0h = (f16*)(ws + (size_t)10 * P0 * 64);
  f16* v0h = q0h + (size_t)2 * P0 * 64;
  f16* qh1 = q0h + (size_t)10 * P0 * 64;
  f16* vh1 = qh1 + (size_t)2 * (P0 / 4) * 64;
  f16* qh2 = vh1 + (size_t)8 * (P0 / 4) * 64;
  f16* vh2 = qh2 + (size_t)2 * (P0 / 16) * 64;
  f16* qh3 = vh2 + (size_t)8 * (P0 / 16) * 64;
  f16* vh3 = qh3 + (size_t)2 * (P0 / 64) * 64;
  f16* wh  = vh3 + (size_t)8 * (P0 / 64) * 64;   // 8192 f16

  // 0) one-shot weight conversion
  prep_weights<<<8, 256, 0, stream>>>(pw, wh);

  // 1) projection via MFMA, fused level-0 norm+f16 (4000 blocks x 64 px)
  proj_mfma<<<4000, 256, 0, stream>>>(query, values, wh, pb, q0, q0h, P0);

  // 2) fused pool+norm chain: one dispatch produces levels 1-3 f16
  pool_all<<<1000, 256, 0, stream>>>(q0, qh1, qh2, qh3);

  // 3) correlation (output tuple concatenated flat)
  float* out0 = out;
  float* out1 = out0 + (size_t)B * N * P0 * 81;
  float* out2 = out1 + (size_t)B * N * (P0 / 4) * 25;
  float* out3 = out2 + (size_t)B * N * (P0 / 16) * 9;
  // waves = 8*H*T; blocks = waves/4 (all divisible by 8)
  corr_mfma<4><<<8 * 160 * 10 / 4, 256, 0, stream>>>(q0h, v0h, out0, 160, 160, 10);
  corr_mfma<2><<<8 * 80 * 5 / 4, 256, 0, stream>>>(qh1, vh1, out1, 80, 80, 5);
  corr_mfma<1><<<8 * 40 * 3 / 4, 256, 0, stream>>>(qh2, vh2, out2, 40, 40, 3);
  corr_mfma<1><<<8 * 20 * 2 / 4, 256, 0, stream>>>(qh3, vh3, out3, 20, 20, 2);
}

// Round 4
// 308.554 us; speedup vs baseline: 1.0789x; 1.0432x over previous
//
#include <hip/hip_runtime.h>

// CorrelationPyramid on MI355X — round 8: LDS-weight projection +
// coalesced-store correlation.
//
// Round-7 post-mortem: proj stuck ~84us/1.9TB/s with VGPR=52 — the per-kc
// WEIGHT loads went to global and the compiler serialized {load->wait->MFMA}
// per kc. r4 (fastest proj, 76us) had weights in LDS. Restored here on top of
// r7's coalesced float4 input staging.
// The larger target: ~200us of the 322 total hides in sub-top-5 dispatches.
// corr wrote 66MB (L0) via scalar 4-B stores at ~324-B pixel stride — up to
// 64 distinct 64-B sectors PER STORE INSTR (16x the L2 request rate of a
// coalesced store), 36 such stores per wave. Now: results staged in a
// wave-private padded LDS tile (no barrier), then copied out with
// fully-coalesced 256-B store instructions.
//
// Pipeline (7 dispatches):
//   0) prep_weights: one-shot fp32 -> f16 of the 64x128 projection matrix.
//   1) proj_mfma   : block = 64 px x 128 ch. Stage: 8x float4/thread into
//                    fp32 LDS [c][68] with rotation swizzle
//                    x=(px+8*((c>>3)&3))&63 (write & read agree; 2-way max =
//                    free). Weights f16 staged to LDS stride-136 (r4 layout).
//                    One barrier. MFMA + fused L0 normalize + f16 epilogue.
//   2) pool_all    : fused 4x4 pool chain + per-level normalize -> f16.
//   3) corr_mfma<R> x4: one WAVE per (bn, h, w-tile); per-dyi band MFMAs
//                    write valid (px,dy,dx) values into wave-private LDS
//                    [16][PS]; after the dyi loop a coalesced copy-out emits
//                    vp*DD contiguous floats per tile. bn = blockIdx%8 pins
//                    each value image to one XCD's L2.

typedef _Float16 f16;
typedef _Float16 f16x4 __attribute__((ext_vector_type(4)));
typedef _Float16 f16x8 __attribute__((ext_vector_type(8)));
typedef float f32x4 __attribute__((ext_vector_type(4)));

#define EPSN 1e-12f

// ---------------- one-shot weight fp32 -> f16 ----------------
__global__ __launch_bounds__(256) void prep_weights(
    const float* __restrict__ wt, f16* __restrict__ wh) {
  int gid = blockIdx.x * 256 + threadIdx.x;   // 2048 threads x 4 elems = 8192
  float4 w = *(const float4*)(wt + gid * 4);
  f16x4 h;
  h[0] = (f16)w.x; h[1] = (f16)w.y; h[2] = (f16)w.z; h[3] = (f16)w.w;
  *(f16x4*)(wh + gid * 4) = h;
}

// ---------------- projection via MFMA, fused level-0 normalize ----------------
// Block = 256 threads = 4 waves, covers 64 consecutive pixels x 128 channels.
// LDS: fp32 x [128][68] swizzled + f16 weights [64][136].
#define LROW 68
#define WS 136

__global__ __launch_bounds__(256, 3) void proj_mfma(
    const float* __restrict__ xq, const float* __restrict__ xv,
    const f16* __restrict__ wh, const float* __restrict__ bias,
    float* __restrict__ outf, f16* __restrict__ outh, int P) {
  __shared__ float xs[128 * LROW];   // 34,816 B
  __shared__ f16 wsh[64 * WS];       // 17,408 B

  int bid = blockIdx.x;
  int img = bid / 400;           // 10 images: 0,1 = query; 2..9 = values
  int p0 = (bid - img * 400) * 64;
  const float* xsrc = (img < 2) ? (xq + (size_t)img * 128 * P)
                                : (xv + (size_t)(img - 2) * 128 * P);

  int tid = threadIdx.x;
  int lane = tid & 63;
  int wv = tid >> 6;
  int cl = lane & 15;
  int quad = lane >> 4;

  // ---- stage weights: 1024 f16x8 chunks, coalesced, stride-136 rows ----
  for (int m = tid; m < 1024; m += 256) {
    int o = m >> 4, kk = (m & 15) * 8;
    *(f16x8*)(wsh + o * WS + kk) = *(const f16x8*)(wh + o * 128 + kk);
  }

  // ---- stage x: coalesced float4 loads, swizzled b128 LDS writes ----
  {
    int cb = tid >> 4;            // 0..15
    int pxg = (tid & 15) * 4;     // 0..60
#pragma unroll
    for (int i = 0; i < 8; ++i) {
      int c = cb + 16 * i;
      float4 v = *(const float4*)(xsrc + (size_t)c * P + p0 + pxg);
      int x = (pxg + 8 * ((c >> 3) & 3)) & 63;
      *(float4*)(xs + c * LROW + x) = v;
    }
  }
  __syncthreads();

  // ---- MFMA: wave wv owns pixel tile [wv*16, wv*16+16) ----
  f32x4 acc[4];
#pragma unroll
  for (int m = 0; m < 4; ++m) acc[m] = (f32x4)0.f;

  int pxl = wv * 16 + cl;                       // local pixel this lane owns
  int xr = (pxl + 8 * quad) & 63;               // rot(c) == 8*quad for frags

#pragma unroll
  for (int kc = 0; kc < 4; ++kc) {
    f16x8 bfr;
#pragma unroll
    for (int k = 0; k < 8; ++k) {
      int c = kc * 32 + quad * 8 + k;
      bfr[k] = (f16)xs[c * LROW + xr];
    }
    f16x8 afr[4];
#pragma unroll
    for (int mt = 0; mt < 4; ++mt)
      afr[mt] = *(const f16x8*)(wsh + (mt * 16 + cl) * WS + kc * 32 + quad * 8);
#pragma unroll
    for (int mt = 0; mt < 4; ++mt)
      acc[mt] = __builtin_amdgcn_mfma_f32_16x16x32_f16(afr[mt], bfr, acc[mt], 0, 0, 0);
  }

  float4 bi[4];
#pragma unroll
  for (int mt = 0; mt < 4; ++mt) bi[mt] = *(const float4*)(bias + mt * 16 + quad * 4);

  int px = p0 + pxl;
  float ss = 0.f;
#pragma unroll
  for (int mt = 0; mt < 4; ++mt) {
    acc[mt][0] += bi[mt].x;
    acc[mt][1] += bi[mt].y;
    acc[mt][2] += bi[mt].z;
    acc[mt][3] += bi[mt].w;
#pragma unroll
    for (int r = 0; r < 4; ++r) ss = fmaf(acc[mt][r], acc[mt][r], ss);
  }
  ss += __shfl_xor(ss, 16, 64);
  ss += __shfl_xor(ss, 32, 64);
  float s = 1.0f / fmaxf(sqrtf(ss), EPSN);
  size_t base = ((size_t)img * P + px) * 64;
#pragma unroll
  for (int mt = 0; mt < 4; ++mt) {
    *(float4*)(outf + base + mt * 16 + quad * 4) =
        make_float4(acc[mt][0], acc[mt][1], acc[mt][2], acc[mt][3]);
    f16x4 hn;
    hn[0] = (f16)(acc[mt][0] * s);
    hn[1] = (f16)(acc[mt][1] * s);
    hn[2] = (f16)(acc[mt][2] * s);
    hn[3] = (f16)(acc[mt][3] * s);
    *(f16x4*)(outh + base + mt * 16 + quad * 4) = hn;
  }
}

// ---------------- fused 4x4 pool + per-level L2-normalize -> f16 -------------
// One thread = 4 channels (c4) of one L2 (40x40) output pixel.
// 16-lane group (c4=0..15) = all 64 channels of that pixel.
// 4 groups of a wave (g = (tid>>4)&3) = a 2x2 block of L2 pixels -> one L3
// pixel via shfl_xor(16/32).
// Emits: qh1 (80x80 f16 norm), qh2 (40x40), qh3 (20x20). No fp32 intermediates.
__global__ __launch_bounds__(256) void pool_all(
    const float* __restrict__ q0, f16* __restrict__ qh1,
    f16* __restrict__ qh2, f16* __restrict__ qh3) {
  int gid = blockIdx.x * 256 + threadIdx.x;   // total = 10*20*20*64 = 256000
  int c4 = gid & 15;
  int g = (gid >> 4) & 3;
  int idx = gid >> 6;            // [0, 4000)
  int w3 = idx % 20;
  int t = idx / 20;
  int h3 = t % 20;
  int img = t / 20;
  int h2 = 2 * h3 + (g >> 1);
  int w2 = 2 * w3 + (g & 1);

  const float4* in4 = (const float4*)q0;
  size_t base = ((size_t)(img * 160 + 4 * h2) * 160 + 4 * w2) * 16 + c4;
  float4 a[16];
#pragma unroll
  for (int i = 0; i < 4; ++i)
#pragma unroll
    for (int j = 0; j < 4; ++j)
      a[i * 4 + j] = in4[base + (size_t)i * 160 * 16 + j * 16];

  // level-1 pixels (2x2 of them) + level-2 pixel
  float4 v1[4];
  float4 q2v = make_float4(0.f, 0.f, 0.f, 0.f);
#pragma unroll
  for (int i1 = 0; i1 < 2; ++i1)
#pragma unroll
    for (int j1 = 0; j1 < 2; ++j1) {
      float4 s00 = a[(2 * i1) * 4 + 2 * j1];
      float4 s01 = a[(2 * i1) * 4 + 2 * j1 + 1];
      float4 s10 = a[(2 * i1 + 1) * 4 + 2 * j1];
      float4 s11 = a[(2 * i1 + 1) * 4 + 2 * j1 + 1];
      float4 r;
      r.x = 0.25f * (s00.x + s01.x + s10.x + s11.x);
      r.y = 0.25f * (s00.y + s01.y + s10.y + s11.y);
      r.z = 0.25f * (s00.z + s01.z + s10.z + s11.z);
      r.w = 0.25f * (s00.w + s01.w + s10.w + s11.w);
      v1[i1 * 2 + j1] = r;
      q2v.x += r.x; q2v.y += r.y; q2v.z += r.z; q2v.w += r.w;
    }
  q2v.x *= 0.25f; q2v.y *= 0.25f; q2v.z *= 0.25f; q2v.w *= 0.25f;

  // level-1: normalize + write f16
#pragma unroll
  for (int i1 = 0; i1 < 2; ++i1)
#pragma unroll
    for (int j1 = 0; j1 < 2; ++j1) {
      float4 r = v1[i1 * 2 + j1];
      float ss = fmaf(r.x, r.x, fmaf(r.y, r.y, fmaf(r.z, r.z, r.w * r.w)));
      ss += __shfl_xor(ss, 1, 64);
      ss += __shfl_xor(ss, 2, 64);
      ss += __shfl_xor(ss, 4, 64);
      ss += __shfl_xor(ss, 8, 64);
      float s = 1.0f / fmaxf(sqrtf(ss), EPSN);
      int y1 = 2 * h2 + i1, x1 = 2 * w2 + j1;
      f16x4 h;
      h[0] = (f16)(r.x * s); h[1] = (f16)(r.y * s);
      h[2] = (f16)(r.z * s); h[3] = (f16)(r.w * s);
      *(f16x4*)(qh1 + ((size_t)(img * 80 + y1) * 80 + x1) * 64 + c4 * 4) = h;
    }

  // level-2: normalize + write f16
  {
    float ss = fmaf(q2v.x, q2v.x, fmaf(q2v.y, q2v.y, fmaf(q2v.z, q2v.z, q2v.w * q2v.w)));
    ss += __shfl_xor(ss, 1, 64);
    ss += __shfl_xor(ss, 2, 64);
    ss += __shfl_xor(ss, 4, 64);
    ss += __shfl_xor(ss, 8, 64);
    float s = 1.0f / fmaxf(sqrtf(ss), EPSN);
    f16x4 h;
    h[0] = (f16)(q2v.x * s); h[1] = (f16)(q2v.y * s);
    h[2] = (f16)(q2v.z * s); h[3] = (f16)(q2v.w * s);
    *(f16x4*)(qh2 + ((size_t)(img * 40 + h2) * 40 + w2) * 64 + c4 * 4) = h;
  }

  // level-3: cross-group (2x2 L2 pixels) average, normalize, write from g==0
  {
    float4 q3v;
    q3v.x = q2v.x + __shfl_xor(q2v.x, 16, 64);
    q3v.y = q2v.y + __shfl_xor(q2v.y, 16, 64);
    q3v.z = q2v.z + __shfl_xor(q2v.z, 16, 64);
    q3v.w = q2v.w + __shfl_xor(q2v.w, 16, 64);
    q3v.x += __shfl_xor(q3v.x, 32, 64);
    q3v.y += __shfl_xor(q3v.y, 32, 64);
    q3v.z += __shfl_xor(q3v.z, 32, 64);
    q3v.w += __shfl_xor(q3v.w, 32, 64);
    q3v.x *= 0.25f; q3v.y *= 0.25f; q3v.z *= 0.25f; q3v.w *= 0.25f;
    float ss = fmaf(q3v.x, q3v.x, fmaf(q3v.y, q3v.y, fmaf(q3v.z, q3v.z, q3v.w * q3v.w)));
    ss += __shfl_xor(ss, 1, 64);
    ss += __shfl_xor(ss, 2, 64);
    ss += __shfl_xor(ss, 4, 64);
    ss += __shfl_xor(ss, 8, 64);
    float s = 1.0f / fmaxf(sqrtf(ss), EPSN);
    if (g == 0) {
      f16x4 h;
      h[0] = (f16)(q3v.x * s); h[1] = (f16)(q3v.y * s);
      h[2] = (f16)(q3v.z * s); h[3] = (f16)(q3v.w * s);
      *(f16x4*)(qh3 + ((size_t)(img * 20 + h3) * 20 + w3) * 64 + c4 * 4) = h;
    }
  }
}

// ---------------- correlation: one wave per (bn, h, w-tile) ----------------
// Band tiles: T0 cols (w0-R+cl) mod W -> D rows 0-7 (quads 0,1),
// dxi = r - cl + 2R;  T1 cols (w0+R+cl) mod W -> rows 8-15 (quads 2,3),
// dxi = r - cl.  Exact partition for R <= 4; each (px,dy,dx) produced exactly
// once. Valid values are staged into a wave-private LDS tile [16][PS]
// (no barrier needed; same-wave ds ordering + compiler waitcnt), then copied
// out COALESCED: vp*DD contiguous floats per tile, 256 B per store instr.
// C/D layout: col = lane&15, row = (lane>>4)*4 + reg.
template <int R>
__global__ __launch_bounds__(256, 4) void corr_mfma(
    const f16* __restrict__ qh, const f16* __restrict__ vh,
    float* __restrict__ out, int H, int W, int T) {
  constexpr int D = 2 * R + 1, DD = D * D;
  constexpr int PS = (DD + 3) & ~3;           // padded per-pixel stride
  __shared__ float lw[4 * 16 * PS];

  int bn = blockIdx.x & 7;               // 8 bn values -> 8 XCDs (heuristic)
  int wv = threadIdx.x >> 6;
  int widx = (blockIdx.x >> 3) * 4 + wv; // [0, H*T)
  int h = widx / T;
  int wt = widx - h * T;
  int lane = threadIdx.x & 63;
  int cl = lane & 15, quad = lane >> 4;
  int b = bn >> 2;
  int w0 = wt * 16;
  float* lwv = lw + wv * 16 * PS;        // wave-private region

  // A fragments (q row), loaded once
  int ap = w0 + cl; if (ap >= W) ap = W - 1;   // clamp partial tile
  const f16* qp = qh + ((size_t)(b * H + h) * W + ap) * 64 + quad * 8;
  f16x8 a0 = *(const f16x8*)qp;
  f16x8 a1 = *(const f16x8*)(qp + 32);

  // B pixel offsets (roll wraparound), fixed across dy
  int c0 = w0 - R + cl; if (c0 < 0) c0 += W; if (c0 >= W) c0 -= W;
  int c1 = w0 + R + cl; if (c1 >= W) c1 -= W;
  int b0off = c0 * 64 + quad * 8;
  int b1off = c1 * 64 + quad * 8;

  int rbase = quad * 4;
  int base_dxi = rbase - cl + ((quad < 2) ? 2 * R : 0);

  for (int dyi = 0; dyi < D; ++dyi) {
    int h2 = h - dyi + R; if (h2 < 0) h2 += H; else if (h2 >= H) h2 -= H;
    const f16* vrow = vh + ((size_t)(bn * H + h2) * W) * 64;
    f16x8 b0a = *(const f16x8*)(vrow + b0off);
    f16x8 b0b = *(const f16x8*)(vrow + b0off + 32);
    f16x8 b1a = *(const f16x8*)(vrow + b1off);
    f16x8 b1b = *(const f16x8*)(vrow + b1off + 32);
    f32x4 A0 = __builtin_amdgcn_mfma_f32_16x16x32_f16(a0, b0a, (f32x4)0.f, 0, 0, 0);
    A0 = __builtin_amdgcn_mfma_f32_16x16x32_f16(a1, b0b, A0, 0, 0, 0);
    f32x4 A1 = __builtin_amdgcn_mfma_f32_16x16x32_f16(a0, b1a, (f32x4)0.f, 0, 0, 0);
    A1 = __builtin_amdgcn_mfma_f32_16x16x32_f16(a1, b1b, A1, 0, 0, 0);
#pragma unroll
    for (int rr = 0; rr < 4; ++rr) {
      int dxi = base_dxi + rr;
      float val = (quad < 2) ? A0[rr] : A1[rr];
      if ((unsigned)dxi <= (unsigned)(2 * R))
        lwv[(rbase + rr) * PS + dyi * D + dxi] = val;
    }
  }

  // coalesced copy-out: vp*DD contiguous floats, 64 lanes per instr
  int vp = W - w0; if (vp > 16) vp = 16;
  float* ob = out + ((size_t)(bn * H + h) * W + w0) * DD;
  int tot = vp * DD;
  for (int g = lane; g < tot; g += 64) {
    int pl = g / DD;                      // constexpr divisor -> magic mul
    int rem = g - pl * DD;
    ob[g] = lwv[pl * PS + rem];
  }
}

extern "C" void kernel_launch(void* const* d_in, const int* in_sizes, int n_in,
                              void* d_out, int out_size, void* d_ws, size_t ws_size,
                              hipStream_t stream) {
  const float* query  = (const float*)d_in[0];   // [2,128,160,160]
  const float* values = (const float*)d_in[1];   // [2,4,128,160,160]
  const float* pw     = (const float*)d_in[2];   // [64,128]
  const float* pb     = (const float*)d_in[3];   // [64]
  float* out = (float*)d_out;
  float* ws  = (float*)d_ws;

  const int B = 2, N = 4;
  const int P0 = 160 * 160;

  // Workspace layout (floats):
  //   [0, 10*P0*64)            q0+v0 un-normalized fp32 NHWC (proj out, pool in)
  //   then level-0 f16 (10 images), levels 1-3 f16 (10 images each), wh.
  float* q0 = ws;
  f16* q0h = (f16*)(ws + (size_t)10 * P0 * 64);
  f16* v0h = q0h + (size_t)2 * P0 * 64;
  f16* qh1 = q0h + (size_t)10 * P0 * 64;
  f16* vh1 = qh1 + (size_t)2 * (P0 / 4) * 64;
  f16* qh2 = vh1 + (size_t)8 * (P0 / 4) * 64;
  f16* vh2 = qh2 + (size_t)2 * (P0 / 16) * 64;
  f16* qh3 = vh2 + (size_t)8 * (P0 / 16) * 64;
  f16* vh3 = qh3 + (size_t)2 * (P0 / 64) * 64;
  f16* wh  = vh3 + (size_t)8 * (P0 / 64) * 64;   // 8192 f16

  // 0) one-shot weight conversion
  prep_weights<<<8, 256, 0, stream>>>(pw, wh);

  // 1) projection via MFMA, fused level-0 norm+f16 (4000 blocks x 64 px)
  proj_mfma<<<4000, 256, 0, stream>>>(query, values, wh, pb, q0, q0h, P0);

  // 2) fused pool+norm chain: one dispatch produces levels 1-3 f16
  pool_all<<<1000, 256, 0, stream>>>(q0, qh1, qh2, qh3);

  // 3) correlation (output tuple concatenated flat)
  float* out0 = out;
  float* out1 = out0 + (size_t)B * N * P0 * 81;
  float* out2 = out1 + (size_t)B * N * (P0 / 4) * 25;
  float* out3 = out2 + (size_t)B * N * (P0 / 16) * 9;
  // waves = 8*H*T; blocks = waves/4 (all divisible by 8)
  corr_mfma<4><<<8 * 160 * 10 / 4, 256, 0, stream>>>(q0h, v0h, out0, 160, 160, 10);
  corr_mfma<2><<<8 * 80 * 5 / 4, 256, 0, stream>>>(qh1, vh1, out1, 80, 80, 5);
  corr_mfma<1><<<8 * 40 * 3 / 4, 256, 0, stream>>>(qh2, vh2, out2, 40, 40, 3);
  corr_mfma<1><<<8 * 20 * 2 / 4, 256, 0, stream>>>(qh3, vh3, out3, 20, 20, 2);
}

// Round 5
// 307.883 us; speedup vs baseline: 1.0813x; 1.0022x over previous
//
#include <hip/hip_runtime.h>

// CorrelationPyramid on MI355X — round 9: proj+pool megakernel.
//
// Round-8 post-mortem: four structurally different proj variants all pin at
// 76-90us / ~2.1 TB/s with all pipes idle — so shrink proj's JOB instead of
// its form. Block = one 8x8 pixel tile: the tile contains exactly its 4x4 L1,
// 2x2 L2 and ONE L3 pixel, so the entire pooling pyramid closes inside the
// block (LDS accumulator aliased into the dead weight region). Deletes the
// 65 MB fp32 outf write, the 65 MB pool_all re-read, its 11 MB write and one
// dispatch: pipeline traffic -130 MB.
//
// Pipeline (6 dispatches):
//   0) prep_weights : one-shot fp32 -> f16 of the 64x128 projection matrix.
//   1) proj_pool    : block = 8x8 px x 128 ch. Stage: coalesced float4 into
//                     fp32 LDS [c][68], rotation swizzle x=(p+8*((c>>3)&3))&63
//                     (write & read agree). Weights f16 in LDS stride-136.
//                     MFMA 16x16x32 -> biased fp32 acc. Epilogue: L0
//                     normalize+f16 store; biased acc -> LDS [px][68];
//                     in-block 2x2/4x4/8x8 pooling with per-level L2
//                     normalize -> f16 stores for levels 1-3.
//   2) corr_mfma<R> x4: one WAVE per (bn, h, w-tile); band-tile MFMAs, valid
//                     values staged in wave-private LDS then copied out with
//                     coalesced 256-B stores. bn = blockIdx%8 pins each value
//                     image to one XCD's L2.

typedef _Float16 f16;
typedef _Float16 f16x4 __attribute__((ext_vector_type(4)));
typedef _Float16 f16x8 __attribute__((ext_vector_type(8)));
typedef float f32x4 __attribute__((ext_vector_type(4)));

#define EPSN 1e-12f

// ---------------- one-shot weight fp32 -> f16 ----------------
__global__ __launch_bounds__(256) void prep_weights(
    const float* __restrict__ wt, f16* __restrict__ wh) {
  int gid = blockIdx.x * 256 + threadIdx.x;   // 2048 threads x 4 elems = 8192
  float4 w = *(const float4*)(wt + gid * 4);
  f16x4 h;
  h[0] = (f16)w.x; h[1] = (f16)w.y; h[2] = (f16)w.z; h[3] = (f16)w.w;
  *(f16x4*)(wh + gid * 4) = h;
}

// ---------------- fused projection + pyramid pooling ----------------
// Block = 256 threads = 4 waves = one 8x8 pixel tile of one image.
// LDS: fp32 xs[128][68] (stage; later reused for l3buf) +
//      f16 wsh[64][136]  (weights; later reused as fp32 acc[64 px][68]).
#define LROW 68
#define WS 136

__global__ __launch_bounds__(256, 3) void proj_pool(
    const float* __restrict__ xq, const float* __restrict__ xv,
    const f16* __restrict__ wh, const float* __restrict__ bias,
    f16* __restrict__ h0, f16* __restrict__ h1,
    f16* __restrict__ h2, f16* __restrict__ h3, int P) {
  __shared__ float xs[128 * LROW];   // 34,816 B
  __shared__ f16 wsh[64 * WS];       // 17,408 B
  float* accbuf = (float*)wsh;       // 64 px x 68 floats = 17,408 B (aliased)
  float* l3buf = xs;                 // 4 waves x 16 x float4 = 1 KB (aliased)

  int bid = blockIdx.x;
  int img = bid / 400;               // 10 images: 0,1 = query; 2..9 = values
  int t = bid - img * 400;           // 20x20 tiles of 8x8 px
  int ty = t / 20, tx = t - ty * 20;
  int py0 = ty * 8, px0 = tx * 8;
  const float* xsrc = (img < 2) ? (xq + (size_t)img * 128 * P)
                                : (xv + (size_t)(img - 2) * 128 * P);

  int tid = threadIdx.x;
  int lane = tid & 63;
  int wv = tid >> 6;
  int cl = lane & 15;
  int quad = lane >> 4;

  // ---- stage weights: coalesced f16x8, stride-136 rows ----
  for (int m = tid; m < 1024; m += 256) {
    int o = m >> 4, kk = (m & 15) * 8;
    *(f16x8*)(wsh + o * WS + kk) = *(const f16x8*)(wh + o * 128 + kk);
  }

  // ---- stage x: coalesced float4 loads, swizzled LDS writes ----
  {
    int cb = tid >> 4;               // 0..15
    int sub = tid & 15;
    int row = sub >> 1, hf = sub & 1;
#pragma unroll
    for (int i = 0; i < 8; ++i) {
      int c = cb + 16 * i;
      float4 v = *(const float4*)(xsrc + (size_t)c * P + (py0 + row) * 160 + px0 + hf * 4);
      int p = row * 8 + hf * 4;      // tile-local pixel (multiple of 4)
      int x = (p + 8 * ((c >> 3) & 3)) & 63;
      *(float4*)(xs + c * LROW + x) = v;
    }
  }
  __syncthreads();   // #1: stage -> MFMA

  // ---- MFMA: wave wv owns tile-local pixels [wv*16, wv*16+16) ----
  f32x4 acc[4];
#pragma unroll
  for (int m = 0; m < 4; ++m) acc[m] = (f32x4)0.f;

  int pxl = wv * 16 + cl;                  // tile-local pixel this lane owns
  int xr = (pxl + 8 * quad) & 63;          // rot(c) == 8*quad for our frags

#pragma unroll
  for (int kc = 0; kc < 4; ++kc) {
    f16x8 bfr;
#pragma unroll
    for (int k = 0; k < 8; ++k) {
      int c = kc * 32 + quad * 8 + k;
      bfr[k] = (f16)xs[c * LROW + xr];
    }
    f16x8 afr[4];
#pragma unroll
    for (int mt = 0; mt < 4; ++mt)
      afr[mt] = *(const f16x8*)(wsh + (mt * 16 + cl) * WS + kc * 32 + quad * 8);
#pragma unroll
    for (int mt = 0; mt < 4; ++mt)
      acc[mt] = __builtin_amdgcn_mfma_f32_16x16x32_f16(afr[mt], bfr, acc[mt], 0, 0, 0);
  }

  float4 bi[4];
#pragma unroll
  for (int mt = 0; mt < 4; ++mt) bi[mt] = *(const float4*)(bias + mt * 16 + quad * 4);

  __syncthreads();   // #2: all wsh/xs reads done before accbuf overwrite

  // ---- epilogue A: bias, stash un-normalized acc, L0 normalize + store ----
  float ss = 0.f;
#pragma unroll
  for (int mt = 0; mt < 4; ++mt) {
    acc[mt][0] += bi[mt].x;
    acc[mt][1] += bi[mt].y;
    acc[mt][2] += bi[mt].z;
    acc[mt][3] += bi[mt].w;
    *(float4*)(accbuf + pxl * LROW + mt * 16 + quad * 4) =
        make_float4(acc[mt][0], acc[mt][1], acc[mt][2], acc[mt][3]);
#pragma unroll
    for (int r = 0; r < 4; ++r) ss = fmaf(acc[mt][r], acc[mt][r], ss);
  }
  ss += __shfl_xor(ss, 16, 64);
  ss += __shfl_xor(ss, 32, 64);
  float s = 1.0f / fmaxf(sqrtf(ss), EPSN);
  {
    int gp = (py0 + (pxl >> 3)) * 160 + px0 + (pxl & 7);
    size_t base = ((size_t)img * P + gp) * 64;
#pragma unroll
    for (int mt = 0; mt < 4; ++mt) {
      f16x4 hn;
      hn[0] = (f16)(acc[mt][0] * s);
      hn[1] = (f16)(acc[mt][1] * s);
      hn[2] = (f16)(acc[mt][2] * s);
      hn[3] = (f16)(acc[mt][3] * s);
      *(f16x4*)(h0 + base + mt * 16 + quad * 4) = hn;
    }
  }
  __syncthreads();   // #3: accbuf visible to pool phase

  // ---- pool phase ----
  // wave wv owns L2 pixel (r2,c2) = (wv>>1, wv&1); lane group g = quad owns
  // L1 pixel (2r2+(g>>1), 2c2+(g&1)); 16 lanes (c4=cl) = 64 channels.
  int r2 = wv >> 1, c2 = wv & 1;
  int g = quad, c4 = cl;
  int r1 = 2 * r2 + (g >> 1), c1 = 2 * c2 + (g & 1);
  int p00 = (2 * r1) * 8 + 2 * c1;

  float4 s00 = *(const float4*)(accbuf + p00 * LROW + c4 * 4);
  float4 s01 = *(const float4*)(accbuf + (p00 + 1) * LROW + c4 * 4);
  float4 s10 = *(const float4*)(accbuf + (p00 + 8) * LROW + c4 * 4);
  float4 s11 = *(const float4*)(accbuf + (p00 + 9) * LROW + c4 * 4);
  float4 v1;
  v1.x = 0.25f * (s00.x + s01.x + s10.x + s11.x);
  v1.y = 0.25f * (s00.y + s01.y + s10.y + s11.y);
  v1.z = 0.25f * (s00.z + s01.z + s10.z + s11.z);
  v1.w = 0.25f * (s00.w + s01.w + s10.w + s11.w);

  // L1 normalize + store
  {
    float s1 = fmaf(v1.x, v1.x, fmaf(v1.y, v1.y, fmaf(v1.z, v1.z, v1.w * v1.w)));
    s1 += __shfl_xor(s1, 1, 64);
    s1 += __shfl_xor(s1, 2, 64);
    s1 += __shfl_xor(s1, 4, 64);
    s1 += __shfl_xor(s1, 8, 64);
    float sc = 1.0f / fmaxf(sqrtf(s1), EPSN);
    f16x4 h;
    h[0] = (f16)(v1.x * sc); h[1] = (f16)(v1.y * sc);
    h[2] = (f16)(v1.z * sc); h[3] = (f16)(v1.w * sc);
    *(f16x4*)(h1 + ((size_t)(img * 80 + ty * 4 + r1) * 80 + tx * 4 + c1) * 64 + c4 * 4) = h;
  }

  // L2: average the wave's 4 L1 pixels via shfl 16/32
  float4 q2v;
  q2v.x = v1.x + __shfl_xor(v1.x, 16, 64);
  q2v.y = v1.y + __shfl_xor(v1.y, 16, 64);
  q2v.z = v1.z + __shfl_xor(v1.z, 16, 64);
  q2v.w = v1.w + __shfl_xor(v1.w, 16, 64);
  q2v.x += __shfl_xor(q2v.x, 32, 64);
  q2v.y += __shfl_xor(q2v.y, 32, 64);
  q2v.z += __shfl_xor(q2v.z, 32, 64);
  q2v.w += __shfl_xor(q2v.w, 32, 64);
  q2v.x *= 0.25f; q2v.y *= 0.25f; q2v.z *= 0.25f; q2v.w *= 0.25f;

  {
    float s2 = fmaf(q2v.x, q2v.x, fmaf(q2v.y, q2v.y, fmaf(q2v.z, q2v.z, q2v.w * q2v.w)));
    s2 += __shfl_xor(s2, 1, 64);
    s2 += __shfl_xor(s2, 2, 64);
    s2 += __shfl_xor(s2, 4, 64);
    s2 += __shfl_xor(s2, 8, 64);
    float sc = 1.0f / fmaxf(sqrtf(s2), EPSN);
    if (g == 0) {
      f16x4 h;
      h[0] = (f16)(q2v.x * sc); h[1] = (f16)(q2v.y * sc);
      h[2] = (f16)(q2v.z * sc); h[3] = (f16)(q2v.w * sc);
      *(f16x4*)(h2 + ((size_t)(img * 40 + ty * 2 + r2) * 40 + tx * 2 + c2) * 64 + c4 * 4) = h;
      // stash un-normalized L2 value for the L3 reduction
      *(float4*)(l3buf + (wv * 16 + c4) * 4) = q2v;
    }
  }
  __syncthreads();   // #4: l3buf visible

  // L3: one 16-lane group averages the 4 L2 pixels
  if (tid < 16) {
    float4 a0 = *(const float4*)(l3buf + (0 * 16 + tid) * 4);
    float4 a1 = *(const float4*)(l3buf + (1 * 16 + tid) * 4);
    float4 a2 = *(const float4*)(l3buf + (2 * 16 + tid) * 4);
    float4 a3 = *(const float4*)(l3buf + (3 * 16 + tid) * 4);
    float4 q3;
    q3.x = 0.25f * (a0.x + a1.x + a2.x + a3.x);
    q3.y = 0.25f * (a0.y + a1.y + a2.y + a3.y);
    q3.z = 0.25f * (a0.z + a1.z + a2.z + a3.z);
    q3.w = 0.25f * (a0.w + a1.w + a2.w + a3.w);
    float s3 = fmaf(q3.x, q3.x, fmaf(q3.y, q3.y, fmaf(q3.z, q3.z, q3.w * q3.w)));
    s3 += __shfl_xor(s3, 1, 64);
    s3 += __shfl_xor(s3, 2, 64);
    s3 += __shfl_xor(s3, 4, 64);
    s3 += __shfl_xor(s3, 8, 64);
    float sc = 1.0f / fmaxf(sqrtf(s3), EPSN);
    f16x4 h;
    h[0] = (f16)(q3.x * sc); h[1] = (f16)(q3.y * sc);
    h[2] = (f16)(q3.z * sc); h[3] = (f16)(q3.w * sc);
    *(f16x4*)(h3 + ((size_t)(img * 20 + ty) * 20 + tx) * 64 + tid * 4) = h;
  }
}

// ---------------- correlation: one wave per (bn, h, w-tile) ----------------
// Band tiles: T0 cols (w0-R+cl) mod W -> D rows 0-7 (quads 0,1),
// dxi = r - cl + 2R;  T1 cols (w0+R+cl) mod W -> rows 8-15 (quads 2,3),
// dxi = r - cl.  Exact partition for R <= 4; each (px,dy,dx) produced exactly
// once. Valid values staged into a wave-private LDS tile [16][PS] (no barrier
// needed; same-wave ds ordering), then copied out COALESCED.
// C/D layout: col = lane&15, row = (lane>>4)*4 + reg.
template <int R>
__global__ __launch_bounds__(256, 4) void corr_mfma(
    const f16* __restrict__ qh, const f16* __restrict__ vh,
    float* __restrict__ out, int H, int W, int T) {
  constexpr int D = 2 * R + 1, DD = D * D;
  constexpr int PS = (DD + 3) & ~3;           // padded per-pixel stride
  __shared__ float lw[4 * 16 * PS];

  int bn = blockIdx.x & 7;               // 8 bn values -> 8 XCDs (heuristic)
  int wv = threadIdx.x >> 6;
  int widx = (blockIdx.x >> 3) * 4 + wv; // [0, H*T)
  int h = widx / T;
  int wt = widx - h * T;
  int lane = threadIdx.x & 63;
  int cl = lane & 15, quad = lane >> 4;
  int b = bn >> 2;
  int w0 = wt * 16;
  float* lwv = lw + wv * 16 * PS;        // wave-private region

  // A fragments (q row), loaded once
  int ap = w0 + cl; if (ap >= W) ap = W - 1;   // clamp partial tile
  const f16* qp = qh + ((size_t)(b * H + h) * W + ap) * 64 + quad * 8;
  f16x8 a0 = *(const f16x8*)qp;
  f16x8 a1 = *(const f16x8*)(qp + 32);

  // B pixel offsets (roll wraparound), fixed across dy
  int c0 = w0 - R + cl; if (c0 < 0) c0 += W; if (c0 >= W) c0 -= W;
  int c1 = w0 + R + cl; if (c1 >= W) c1 -= W;
  int b0off = c0 * 64 + quad * 8;
  int b1off = c1 * 64 + quad * 8;

  int rbase = quad * 4;
  int base_dxi = rbase - cl + ((quad < 2) ? 2 * R : 0);

  for (int dyi = 0; dyi < D; ++dyi) {
    int h2 = h - dyi + R; if (h2 < 0) h2 += H; else if (h2 >= H) h2 -= H;
    const f16* vrow = vh + ((size_t)(bn * H + h2) * W) * 64;
    f16x8 b0a = *(const f16x8*)(vrow + b0off);
    f16x8 b0b = *(const f16x8*)(vrow + b0off + 32);
    f16x8 b1a = *(const f16x8*)(vrow + b1off);
    f16x8 b1b = *(const f16x8*)(vrow + b1off + 32);
    f32x4 A0 = __builtin_amdgcn_mfma_f32_16x16x32_f16(a0, b0a, (f32x4)0.f, 0, 0, 0);
    A0 = __builtin_amdgcn_mfma_f32_16x16x32_f16(a1, b0b, A0, 0, 0, 0);
    f32x4 A1 = __builtin_amdgcn_mfma_f32_16x16x32_f16(a0, b1a, (f32x4)0.f, 0, 0, 0);
    A1 = __builtin_amdgcn_mfma_f32_16x16x32_f16(a1, b1b, A1, 0, 0, 0);
#pragma unroll
    for (int rr = 0; rr < 4; ++rr) {
      int dxi = base_dxi + rr;
      float val = (quad < 2) ? A0[rr] : A1[rr];
      if ((unsigned)dxi <= (unsigned)(2 * R))
        lwv[(rbase + rr) * PS + dyi * D + dxi] = val;
    }
  }

  // coalesced copy-out: vp*DD contiguous floats, 64 lanes per instr
  int vp = W - w0; if (vp > 16) vp = 16;
  float* ob = out + ((size_t)(bn * H + h) * W + w0) * DD;
  int tot = vp * DD;
  for (int gg = lane; gg < tot; gg += 64) {
    int pl = gg / DD;                     // constexpr divisor -> magic mul
    int rem = gg - pl * DD;
    ob[gg] = lwv[pl * PS + rem];
  }
}

extern "C" void kernel_launch(void* const* d_in, const int* in_sizes, int n_in,
                              void* d_out, int out_size, void* d_ws, size_t ws_size,
                              hipStream_t stream) {
  const float* query  = (const float*)d_in[0];   // [2,128,160,160]
  const float* values = (const float*)d_in[1];   // [2,4,128,160,160]
  const float* pw     = (const float*)d_in[2];   // [64,128]
  const float* pb     = (const float*)d_in[3];   // [64]
  float* out = (float*)d_out;
  float* ws  = (float*)d_ws;

  const int B = 2, N = 4;
  const int P0 = 160 * 160;

  // Workspace layout (f16): levels 0-3, each 10 images ordered
  // {q_b0, q_b1, v_0..v_7}; then the converted weights.
  f16* h0 = (f16*)ws;
  f16* h1 = h0 + (size_t)10 * P0 * 64;
  f16* h2 = h1 + (size_t)10 * (P0 / 4) * 64;
  f16* h3 = h2 + (size_t)10 * (P0 / 16) * 64;
  f16* wh = h3 + (size_t)10 * (P0 / 64) * 64;   // 8192 f16

  f16* q0h = h0;             f16* v0h = h0 + (size_t)2 * P0 * 64;
  f16* qh1 = h1;             f16* vh1 = h1 + (size_t)2 * (P0 / 4) * 64;
  f16* qh2 = h2;             f16* vh2 = h2 + (size_t)2 * (P0 / 16) * 64;
  f16* qh3 = h3;             f16* vh3 = h3 + (size_t)2 * (P0 / 64) * 64;

  // 0) one-shot weight conversion
  prep_weights<<<8, 256, 0, stream>>>(pw, wh);

  // 1) fused projection + pooling pyramid (4000 blocks x 8x8 px)
  proj_pool<<<4000, 256, 0, stream>>>(query, values, wh, pb, h0, h1, h2, h3, P0);

  // 2) correlation (output tuple concatenated flat)
  float* out0 = out;
  float* out1 = out0 + (size_t)B * N * P0 * 81;
  float* out2 = out1 + (size_t)B * N * (P0 / 4) * 25;
  float* out3 = out2 + (size_t)B * N * (P0 / 16) * 9;
  // waves = 8*H*T; blocks = waves/4 (all divisible by 8)
  corr_mfma<4><<<8 * 160 * 10 / 4, 256, 0, stream>>>(q0h, v0h, out0, 160, 160, 10);
  corr_mfma<2><<<8 * 80 * 5 / 4, 256, 0, stream>>>(qh1, vh1, out1, 80, 80, 5);
  corr_mfma<1><<<8 * 40 * 3 / 4, 256, 0, stream>>>(qh2, vh2, out2, 40, 40, 3);
  corr_mfma<1><<<8 * 20 * 2 / 4, 256, 0, stream>>>(qh3, vh3, out3, 20, 20, 2);
}

// Round 6
// 287.379 us; speedup vs baseline: 1.1584x; 1.0713x over previous
//
#include <hip/hip_runtime.h>

// CorrelationPyramid on MI355X — round 10: XCD-local proj fetch + merged corr.
//
// Round-9 post-mortem: proj_pool's 8x8 tiles read 32 B per 128-B line; the
// other 96 B go to tiles tx+1..3 = consecutive blockIdx = DIFFERENT XCDs ->
// every line fetched 4x (FETCH 64->256 MB measured). Fix: XCD-contiguous
// block swizzle, logical = (pb&7)*500 + (pb>>3): each XCD owns 500
// consecutive tiles (complete row bands), line sharers hit the same L2.
// Also proven: the chip sustained 3.37 TB/s in r9 — the old "2.1 TB/s wall"
// was traffic/locality, not hardware.
// Remaining ~215us is the 4 corr dispatches, each under the top-5 cutoff:
// merged into ONE dispatch (4320 blocks, L0 first; all segments %8==0 so
// bn=(local)&7 keeps XCD pinning), occupancy 4->6 blocks/CU. Next round corr
// is finally visible in counters.
//
// Pipeline (3 dispatches):
//   0) prep_weights : one-shot fp32 -> f16 of the 64x128 projection matrix.
//   1) proj_pool    : block = 8x8 px tile; MFMA projection + full pooling
//                     pyramid closes in-block; emits normalized f16 L0-L3.
//   2) corr_all     : one dispatch, all levels; one WAVE per (bn,h,w-tile);
//                     band-tile MFMAs -> wave-private LDS -> coalesced store.

typedef _Float16 f16;
typedef _Float16 f16x4 __attribute__((ext_vector_type(4)));
typedef _Float16 f16x8 __attribute__((ext_vector_type(8)));
typedef float f32x4 __attribute__((ext_vector_type(4)));

#define EPSN 1e-12f

// ---------------- one-shot weight fp32 -> f16 ----------------
__global__ __launch_bounds__(256) void prep_weights(
    const float* __restrict__ wt, f16* __restrict__ wh) {
  int gid = blockIdx.x * 256 + threadIdx.x;   // 2048 threads x 4 elems = 8192
  float4 w = *(const float4*)(wt + gid * 4);
  f16x4 h;
  h[0] = (f16)w.x; h[1] = (f16)w.y; h[2] = (f16)w.z; h[3] = (f16)w.w;
  *(f16x4*)(wh + gid * 4) = h;
}

// ---------------- fused projection + pyramid pooling ----------------
// Block = 256 threads = 4 waves = one 8x8 pixel tile of one image.
// LDS: fp32 xs[128][68] (stage; later reused for l3buf) +
//      f16 wsh[64][136]  (weights; later reused as fp32 acc[64 px][68]).
#define LROW 68
#define WS 136

__global__ __launch_bounds__(256, 3) void proj_pool(
    const float* __restrict__ xq, const float* __restrict__ xv,
    const f16* __restrict__ wh, const float* __restrict__ bias,
    f16* __restrict__ h0, f16* __restrict__ h1,
    f16* __restrict__ h2, f16* __restrict__ h3, int P) {
  __shared__ float xs[128 * LROW];   // 34,816 B
  __shared__ f16 wsh[64 * WS];       // 17,408 B
  float* accbuf = (float*)wsh;       // 64 px x 68 floats = 17,408 B (aliased)
  float* l3buf = xs;                 // 4 waves x 16 x float4 = 1 KB (aliased)

  // XCD-contiguous swizzle: physical blocks with the same %8 residue (same
  // XCD under round-robin dispatch) cover 500 CONSECUTIVE logical tiles, so
  // the 4 tiles sharing each 128-B input line sit on one XCD's L2.
  int pb = blockIdx.x;
  int bid = (pb & 7) * 500 + (pb >> 3);

  int img = bid / 400;               // 10 images: 0,1 = query; 2..9 = values
  int t = bid - img * 400;           // 20x20 tiles of 8x8 px
  int ty = t / 20, tx = t - ty * 20;
  int py0 = ty * 8, px0 = tx * 8;
  const float* xsrc = (img < 2) ? (xq + (size_t)img * 128 * P)
                                : (xv + (size_t)(img - 2) * 128 * P);

  int tid = threadIdx.x;
  int lane = tid & 63;
  int wv = tid >> 6;
  int cl = lane & 15;
  int quad = lane >> 4;

  // ---- stage weights: coalesced f16x8, stride-136 rows ----
  for (int m = tid; m < 1024; m += 256) {
    int o = m >> 4, kk = (m & 15) * 8;
    *(f16x8*)(wsh + o * WS + kk) = *(const f16x8*)(wh + o * 128 + kk);
  }

  // ---- stage x: coalesced float4 loads, swizzled LDS writes ----
  {
    int cb = tid >> 4;               // 0..15
    int sub = tid & 15;
    int row = sub >> 1, hf = sub & 1;
#pragma unroll
    for (int i = 0; i < 8; ++i) {
      int c = cb + 16 * i;
      float4 v = *(const float4*)(xsrc + (size_t)c * P + (py0 + row) * 160 + px0 + hf * 4);
      int p = row * 8 + hf * 4;      // tile-local pixel (multiple of 4)
      int x = (p + 8 * ((c >> 3) & 3)) & 63;
      *(float4*)(xs + c * LROW + x) = v;
    }
  }
  __syncthreads();   // #1: stage -> MFMA

  // ---- MFMA: wave wv owns tile-local pixels [wv*16, wv*16+16) ----
  f32x4 acc[4];
#pragma unroll
  for (int m = 0; m < 4; ++m) acc[m] = (f32x4)0.f;

  int pxl = wv * 16 + cl;                  // tile-local pixel this lane owns
  int xr = (pxl + 8 * quad) & 63;          // rot(c) == 8*quad for our frags

#pragma unroll
  for (int kc = 0; kc < 4; ++kc) {
    f16x8 bfr;
#pragma unroll
    for (int k = 0; k < 8; ++k) {
      int c = kc * 32 + quad * 8 + k;
      bfr[k] = (f16)xs[c * LROW + xr];
    }
    f16x8 afr[4];
#pragma unroll
    for (int mt = 0; mt < 4; ++mt)
      afr[mt] = *(const f16x8*)(wsh + (mt * 16 + cl) * WS + kc * 32 + quad * 8);
#pragma unroll
    for (int mt = 0; mt < 4; ++mt)
      acc[mt] = __builtin_amdgcn_mfma_f32_16x16x32_f16(afr[mt], bfr, acc[mt], 0, 0, 0);
  }

  float4 bi[4];
#pragma unroll
  for (int mt = 0; mt < 4; ++mt) bi[mt] = *(const float4*)(bias + mt * 16 + quad * 4);

  __syncthreads();   // #2: all wsh/xs reads done before accbuf overwrite

  // ---- epilogue A: bias, stash un-normalized acc, L0 normalize + store ----
  float ss = 0.f;
#pragma unroll
  for (int mt = 0; mt < 4; ++mt) {
    acc[mt][0] += bi[mt].x;
    acc[mt][1] += bi[mt].y;
    acc[mt][2] += bi[mt].z;
    acc[mt][3] += bi[mt].w;
    *(float4*)(accbuf + pxl * LROW + mt * 16 + quad * 4) =
        make_float4(acc[mt][0], acc[mt][1], acc[mt][2], acc[mt][3]);
#pragma unroll
    for (int r = 0; r < 4; ++r) ss = fmaf(acc[mt][r], acc[mt][r], ss);
  }
  ss += __shfl_xor(ss, 16, 64);
  ss += __shfl_xor(ss, 32, 64);
  float s = 1.0f / fmaxf(sqrtf(ss), EPSN);
  {
    int gp = (py0 + (pxl >> 3)) * 160 + px0 + (pxl & 7);
    size_t base = ((size_t)img * P + gp) * 64;
#pragma unroll
    for (int mt = 0; mt < 4; ++mt) {
      f16x4 hn;
      hn[0] = (f16)(acc[mt][0] * s);
      hn[1] = (f16)(acc[mt][1] * s);
      hn[2] = (f16)(acc[mt][2] * s);
      hn[3] = (f16)(acc[mt][3] * s);
      *(f16x4*)(h0 + base + mt * 16 + quad * 4) = hn;
    }
  }
  __syncthreads();   // #3: accbuf visible to pool phase

  // ---- pool phase ----
  // wave wv owns L2 pixel (r2,c2) = (wv>>1, wv&1); lane group g = quad owns
  // L1 pixel (2r2+(g>>1), 2c2+(g&1)); 16 lanes (c4=cl) = 64 channels.
  int r2 = wv >> 1, c2 = wv & 1;
  int g = quad, c4 = cl;
  int r1 = 2 * r2 + (g >> 1), c1 = 2 * c2 + (g & 1);
  int p00 = (2 * r1) * 8 + 2 * c1;

  float4 s00 = *(const float4*)(accbuf + p00 * LROW + c4 * 4);
  float4 s01 = *(const float4*)(accbuf + (p00 + 1) * LROW + c4 * 4);
  float4 s10 = *(const float4*)(accbuf + (p00 + 8) * LROW + c4 * 4);
  float4 s11 = *(const float4*)(accbuf + (p00 + 9) * LROW + c4 * 4);
  float4 v1;
  v1.x = 0.25f * (s00.x + s01.x + s10.x + s11.x);
  v1.y = 0.25f * (s00.y + s01.y + s10.y + s11.y);
  v1.z = 0.25f * (s00.z + s01.z + s10.z + s11.z);
  v1.w = 0.25f * (s00.w + s01.w + s10.w + s11.w);

  // L1 normalize + store
  {
    float s1 = fmaf(v1.x, v1.x, fmaf(v1.y, v1.y, fmaf(v1.z, v1.z, v1.w * v1.w)));
    s1 += __shfl_xor(s1, 1, 64);
    s1 += __shfl_xor(s1, 2, 64);
    s1 += __shfl_xor(s1, 4, 64);
    s1 += __shfl_xor(s1, 8, 64);
    float sc = 1.0f / fmaxf(sqrtf(s1), EPSN);
    f16x4 h;
    h[0] = (f16)(v1.x * sc); h[1] = (f16)(v1.y * sc);
    h[2] = (f16)(v1.z * sc); h[3] = (f16)(v1.w * sc);
    *(f16x4*)(h1 + ((size_t)(img * 80 + ty * 4 + r1) * 80 + tx * 4 + c1) * 64 + c4 * 4) = h;
  }

  // L2: average the wave's 4 L1 pixels via shfl 16/32
  float4 q2v;
  q2v.x = v1.x + __shfl_xor(v1.x, 16, 64);
  q2v.y = v1.y + __shfl_xor(v1.y, 16, 64);
  q2v.z = v1.z + __shfl_xor(v1.z, 16, 64);
  q2v.w = v1.w + __shfl_xor(v1.w, 16, 64);
  q2v.x += __shfl_xor(q2v.x, 32, 64);
  q2v.y += __shfl_xor(q2v.y, 32, 64);
  q2v.z += __shfl_xor(q2v.z, 32, 64);
  q2v.w += __shfl_xor(q2v.w, 32, 64);
  q2v.x *= 0.25f; q2v.y *= 0.25f; q2v.z *= 0.25f; q2v.w *= 0.25f;

  {
    float s2 = fmaf(q2v.x, q2v.x, fmaf(q2v.y, q2v.y, fmaf(q2v.z, q2v.z, q2v.w * q2v.w)));
    s2 += __shfl_xor(s2, 1, 64);
    s2 += __shfl_xor(s2, 2, 64);
    s2 += __shfl_xor(s2, 4, 64);
    s2 += __shfl_xor(s2, 8, 64);
    float sc = 1.0f / fmaxf(sqrtf(s2), EPSN);
    if (g == 0) {
      f16x4 h;
      h[0] = (f16)(q2v.x * sc); h[1] = (f16)(q2v.y * sc);
      h[2] = (f16)(q2v.z * sc); h[3] = (f16)(q2v.w * sc);
      *(f16x4*)(h2 + ((size_t)(img * 40 + ty * 2 + r2) * 40 + tx * 2 + c2) * 64 + c4 * 4) = h;
      // stash un-normalized L2 value for the L3 reduction
      *(float4*)(l3buf + (wv * 16 + c4) * 4) = q2v;
    }
  }
  __syncthreads();   // #4: l3buf visible

  // L3: one 16-lane group averages the 4 L2 pixels
  if (tid < 16) {
    float4 a0 = *(const float4*)(l3buf + (0 * 16 + tid) * 4);
    float4 a1 = *(const float4*)(l3buf + (1 * 16 + tid) * 4);
    float4 a2 = *(const float4*)(l3buf + (2 * 16 + tid) * 4);
    float4 a3 = *(const float4*)(l3buf + (3 * 16 + tid) * 4);
    float4 q3;
    q3.x = 0.25f * (a0.x + a1.x + a2.x + a3.x);
    q3.y = 0.25f * (a0.y + a1.y + a2.y + a3.y);
    q3.z = 0.25f * (a0.z + a1.z + a2.z + a3.z);
    q3.w = 0.25f * (a0.w + a1.w + a2.w + a3.w);
    float s3 = fmaf(q3.x, q3.x, fmaf(q3.y, q3.y, fmaf(q3.z, q3.z, q3.w * q3.w)));
    s3 += __shfl_xor(s3, 1, 64);
    s3 += __shfl_xor(s3, 2, 64);
    s3 += __shfl_xor(s3, 4, 64);
    s3 += __shfl_xor(s3, 8, 64);
    float sc = 1.0f / fmaxf(sqrtf(s3), EPSN);
    f16x4 h;
    h[0] = (f16)(q3.x * sc); h[1] = (f16)(q3.y * sc);
    h[2] = (f16)(q3.z * sc); h[3] = (f16)(q3.w * sc);
    *(f16x4*)(h3 + ((size_t)(img * 20 + ty) * 20 + tx) * 64 + tid * 4) = h;
  }
}

// ---------------- correlation: one wave per (bn, h, w-tile) ----------------
// Band tiles: T0 cols (w0-R+cl) mod W -> D rows 0-7 (quads 0,1),
// dxi = r - cl + 2R;  T1 cols (w0+R+cl) mod W -> rows 8-15 (quads 2,3),
// dxi = r - cl.  Exact partition for R <= 4; each (px,dy,dx) produced exactly
// once. Valid values staged into a wave-private LDS tile [16][PS] (no barrier
// needed; same-wave ds ordering), then copied out COALESCED.
// C/D layout: col = lane&15, row = (lane>>4)*4 + reg.
template <int R>
__device__ __forceinline__ void corr_level(
    const f16* __restrict__ qh, const f16* __restrict__ vh,
    float* __restrict__ out, int H, int W, int T, int blk, float* lw) {
  constexpr int D = 2 * R + 1, DD = D * D;
  constexpr int PS = (DD + 3) & ~3;           // padded per-pixel stride
  int bn = blk & 7;                      // 8 bn values -> 8 XCDs (heuristic)
  int wv = threadIdx.x >> 6;
  int widx = (blk >> 3) * 4 + wv;        // [0, H*T)
  int h = widx / T;
  int wt = widx - h * T;
  int lane = threadIdx.x & 63;
  int cl = lane & 15, quad = lane >> 4;
  int b = bn >> 2;
  int w0 = wt * 16;
  float* lwv = lw + wv * 16 * PS;        // wave-private region

  // A fragments (q row), loaded once
  int ap = w0 + cl; if (ap >= W) ap = W - 1;   // clamp partial tile
  const f16* qp = qh + ((size_t)(b * H + h) * W + ap) * 64 + quad * 8;
  f16x8 a0 = *(const f16x8*)qp;
  f16x8 a1 = *(const f16x8*)(qp + 32);

  // B pixel offsets (roll wraparound), fixed across dy
  int c0 = w0 - R + cl; if (c0 < 0) c0 += W; if (c0 >= W) c0 -= W;
  int c1 = w0 + R + cl; if (c1 >= W) c1 -= W;
  int b0off = c0 * 64 + quad * 8;
  int b1off = c1 * 64 + quad * 8;

  int rbase = quad * 4;
  int base_dxi = rbase - cl + ((quad < 2) ? 2 * R : 0);

  for (int dyi = 0; dyi < D; ++dyi) {
    int h2 = h - dyi + R; if (h2 < 0) h2 += H; else if (h2 >= H) h2 -= H;
    const f16* vrow = vh + ((size_t)(bn * H + h2) * W) * 64;
    f16x8 b0a = *(const f16x8*)(vrow + b0off);
    f16x8 b0b = *(const f16x8*)(vrow + b0off + 32);
    f16x8 b1a = *(const f16x8*)(vrow + b1off);
    f16x8 b1b = *(const f16x8*)(vrow + b1off + 32);
    f32x4 A0 = __builtin_amdgcn_mfma_f32_16x16x32_f16(a0, b0a, (f32x4)0.f, 0, 0, 0);
    A0 = __builtin_amdgcn_mfma_f32_16x16x32_f16(a1, b0b, A0, 0, 0, 0);
    f32x4 A1 = __builtin_amdgcn_mfma_f32_16x16x32_f16(a0, b1a, (f32x4)0.f, 0, 0, 0);
    A1 = __builtin_amdgcn_mfma_f32_16x16x32_f16(a1, b1b, A1, 0, 0, 0);
#pragma unroll
    for (int rr = 0; rr < 4; ++rr) {
      int dxi = base_dxi + rr;
      float val = (quad < 2) ? A0[rr] : A1[rr];
      if ((unsigned)dxi <= (unsigned)(2 * R))
        lwv[(rbase + rr) * PS + dyi * D + dxi] = val;
    }
  }

  // coalesced copy-out: vp*DD contiguous floats, 64 lanes per instr
  int vp = W - w0; if (vp > 16) vp = 16;
  float* ob = out + ((size_t)(bn * H + h) * W + w0) * DD;
  int tot = vp * DD;
  for (int gg = lane; gg < tot; gg += 64) {
    int pl = gg / DD;                     // constexpr divisor -> magic mul
    int rem = gg - pl * DD;
    ob[gg] = lwv[pl * PS + rem];
  }
}

// One dispatch, all levels. Segments (blocks): L0 3200, L1 800, L2 240,
// L3 80 — every base divisible by 8, so (local blk)&7 still tracks the
// hardware's round-robin XCD assignment of global blockIdx.
__global__ __launch_bounds__(256, 6) void corr_all(
    const f16* __restrict__ q0, const f16* __restrict__ v0,
    const f16* __restrict__ q1, const f16* __restrict__ v1,
    const f16* __restrict__ q2, const f16* __restrict__ v2,
    const f16* __restrict__ q3, const f16* __restrict__ v3,
    float* __restrict__ o0, float* __restrict__ o1,
    float* __restrict__ o2, float* __restrict__ o3) {
  __shared__ float lw[4 * 16 * 84];   // max (R=4) wave-private staging, 21.5 KB
  int blk = blockIdx.x;
  if (blk < 3200)      corr_level<4>(q0, v0, o0, 160, 160, 10, blk, lw);
  else if (blk < 4000) corr_level<2>(q1, v1, o1, 80, 80, 5, blk - 3200, lw);
  else if (blk < 4240) corr_level<1>(q2, v2, o2, 40, 40, 3, blk - 4000, lw);
  else                 corr_level<1>(q3, v3, o3, 20, 20, 2, blk - 4240, lw);
}

extern "C" void kernel_launch(void* const* d_in, const int* in_sizes, int n_in,
                              void* d_out, int out_size, void* d_ws, size_t ws_size,
                              hipStream_t stream) {
  const float* query  = (const float*)d_in[0];   // [2,128,160,160]
  const float* values = (const float*)d_in[1];   // [2,4,128,160,160]
  const float* pw     = (const float*)d_in[2];   // [64,128]
  const float* pb     = (const float*)d_in[3];   // [64]
  float* out = (float*)d_out;
  float* ws  = (float*)d_ws;

  const int B = 2, N = 4;
  const int P0 = 160 * 160;

  // Workspace layout (f16): levels 0-3, each 10 images ordered
  // {q_b0, q_b1, v_0..v_7}; then the converted weights.
  f16* h0 = (f16*)ws;
  f16* h1 = h0 + (size_t)10 * P0 * 64;
  f16* h2 = h1 + (size_t)10 * (P0 / 4) * 64;
  f16* h3 = h2 + (size_t)10 * (P0 / 16) * 64;
  f16* wh = h3 + (size_t)10 * (P0 / 64) * 64;   // 8192 f16

  f16* q0h = h0;             f16* v0h = h0 + (size_t)2 * P0 * 64;
  f16* qh1 = h1;             f16* vh1 = h1 + (size_t)2 * (P0 / 4) * 64;
  f16* qh2 = h2;             f16* vh2 = h2 + (size_t)2 * (P0 / 16) * 64;
  f16* qh3 = h3;             f16* vh3 = h3 + (size_t)2 * (P0 / 64) * 64;

  // 0) one-shot weight conversion
  prep_weights<<<8, 256, 0, stream>>>(pw, wh);

  // 1) fused projection + pooling pyramid (4000 blocks x 8x8 px)
  proj_pool<<<4000, 256, 0, stream>>>(query, values, wh, pb, h0, h1, h2, h3, P0);

  // 2) correlation — ONE dispatch, all four levels
  float* out0 = out;
  float* out1 = out0 + (size_t)B * N * P0 * 81;
  float* out2 = out1 + (size_t)B * N * (P0 / 4) * 25;
  float* out3 = out2 + (size_t)B * N * (P0 / 16) * 9;
  corr_all<<<4320, 256, 0, stream>>>(q0h, v0h, qh1, vh1, qh2, vh2, qh3, vh3,
                                     out0, out1, out2, out3);
}